// Round 11
// baseline (302.873 us; speedup 1.0000x reference)
//
#include <hip/hip_runtime.h>
#include <hip/hip_bf16.h>
#include <cfloat>

__device__ __forceinline__ float lrelu(float x, float a) { return x > 0.0f ? x : a * x; }

// fp32 -> bf16 round-to-nearest-even (bit pattern)
__device__ __forceinline__ unsigned short f2bf(float f) {
    unsigned u = __float_as_uint(f);
    unsigned r = (u + 0x7FFFu + ((u >> 16) & 1u)) >> 16;
    return (unsigned short)r;
}
__device__ __forceinline__ float bf2f(unsigned short u) {
    return __uint_as_float((unsigned)u << 16);
}

typedef __attribute__((ext_vector_type(8))) short short8;
typedef __attribute__((ext_vector_type(4))) float f32x4;

#define BN_RSQ 0.99999500003749968750f  // 1/sqrt(1+1e-5)
#define SCAN_B 256

// ---------- fast zero ----------
__global__ void zero_ws(uint4* __restrict__ p, int n16)
{
    int t = blockIdx.x * blockDim.x + threadIdx.x;
    if (t < n16) p[t] = make_uint4(0u, 0u, 0u, 0u);
}

// ---------- fused prep: SAGE W pack + fc1 W pack + GAT lin W packs + edge histogram ----------
__global__ void prep_all(const float* __restrict__ sWl, const float* __restrict__ sWr,
                         unsigned short* __restrict__ Btp,
                         const float* __restrict__ fc1W, unsigned short* __restrict__ Bt1p,
                         const float* __restrict__ g1Wl, const float* __restrict__ g1Wr,
                         unsigned short* __restrict__ Bg1,
                         const float* __restrict__ g2Wl, const float* __restrict__ g2Wr,
                         unsigned short* __restrict__ Bg2,
                         const int* __restrict__ e1d, const int* __restrict__ e2d,
                         const float* __restrict__ ef,
                         int* __restrict__ cnt1, int* __restrict__ cnt2,
                         float* __restrict__ easum, float* __restrict__ eaext, int E)
{
    int idx = blockIdx.x * blockDim.x + threadIdx.x;
    if (idx < 262144) {
        int j = idx & 7, lane = (idx >> 3) & 63, fn = (idx >> 9) & 3, wid = (idx >> 11) & 3, t = idx >> 13;
        int c = wid * 64 + fn * 16 + (lane & 15);
        int k = t * 32 + (lane >> 4) * 8 + j;
        float v = (c < 128) ? sWl[(size_t)k * 128 + c] : sWr[(size_t)k * 128 + (c - 128)];
        Btp[idx] = f2bf(v);
        return;
    }
    idx -= 262144;
    if (idx < 36864) {
        int j = idx & 7, lane = (idx >> 3) & 63, fn = (idx >> 9) & 3, q = idx >> 11;
        int wid = q % 3, t = q / 3;
        int c = wid * 64 + fn * 16 + (lane & 15);
        int k = t * 32 + (lane >> 4) * 8 + j;
        float v = (c < 168 && k < 168) ? fc1W[(size_t)k * 168 + c] : 0.0f;
        Bt1p[idx] = f2bf(v);
        return;
    }
    idx -= 36864;
    if (idx < 2560) {
        int j = idx & 7, lane = (idx >> 3) & 63, fn = idx >> 9;
        int c = fn * 16 + (lane & 15);
        int k = (lane >> 4) * 8 + j;
        float v = 0.0f;
        if (k < 20) v = (c < 40) ? g1Wl[(size_t)k * 40 + c] : g1Wr[(size_t)k * 40 + (c - 40)];
        Bg1[idx] = f2bf(v);
        return;
    }
    idx -= 2560;
    if (idx < 3072) {
        int j = idx & 7, lane = (idx >> 3) & 63, q = idx >> 9;
        int fn = q % 3, t = q / 3;
        int c = fn * 16 + (lane & 15);
        int k = t * 32 + (lane >> 4) * 8 + j;
        float v = 0.0f;
        if (k < 40 && c < 40) v = (c < 20) ? g2Wl[(size_t)k * 20 + c] : g2Wr[(size_t)k * 20 + (c - 20)];
        Bg2[idx] = f2bf(v);
        return;
    }
    idx -= 3072;
    if (idx < E) {
        atomicAdd(&cnt1[e1d[idx]], 1);
        int d2 = e2d[idx];
        atomicAdd(&cnt2[d2], 1);
        float a = ef[idx];
        atomicAdd(&easum[d2], a);
        eaext[idx] = a;
    }
}

// ---------- SAGE GEMM via MFMA: global_load_lds staging (fp32, XOR-swizzled) ----------
// Block: 64 rows x 256 cols, 4 waves. A staged direct-to-LDS (no VGPR roundtrip),
// 16B slots swizzled phys = log ^ (row&7) via PRE-SWIZZLED GLOBAL SOURCE (linear LDS
// dest, rule #21); same XOR applied at ds_read. bf16 conversion at fragment build.
__global__ __launch_bounds__(256) void gemm_sage_mfma(
    const float* __restrict__ A, const unsigned short* __restrict__ Btp,
    unsigned short* __restrict__ P, int M)
{
    __shared__ float As2[2][64][64];
    const int tid = threadIdx.x;
    const int wid = tid >> 6, lane = tid & 63;
    const int m0 = blockIdx.x * 64;
    const int l16 = lane & 15, g = lane >> 4;
    const int colbase = wid * 64 + l16;
    const short8* Bv = reinterpret_cast<const short8*>(Btp);
    const int r4 = lane >> 4;      // row within 4-row group
    const int cgp = lane & 15;     // physical 16B slot

    // per-lane fixed source row/slot (per staging instruction i)
    int srow[4]; const float* sga[4];
#pragma unroll
    for (int i = 0; i < 4; ++i) {
        int row = wid * 16 + i * 4 + r4;
        int cgl = cgp ^ (row & 7);                 // pre-swizzled logical slot
        int ar = m0 + row; if (ar >= M) ar = M - 1; // clamp (only feeds discarded rows)
        srow[i] = row;
        sga[i] = &A[(size_t)ar * 1024 + cgl * 4];
    }

    auto stage = [&](int buf, int k0f) {
#pragma unroll
        for (int i = 0; i < 4; ++i) {
            const float* gp = sga[i] + k0f;
            float* lp = &As2[buf][wid * 16 + i * 4][0];   // wave-uniform base
            __builtin_amdgcn_global_load_lds(
                (const __attribute__((address_space(1))) void*)gp,
                (__attribute__((address_space(3))) void*)lp, 16, 0, 0);
        }
    };

    f32x4 acc[4][4] = {};

    stage(0, 0);
    __syncthreads();

    for (int c = 0; c < 16; ++c) {
        const int buf = c & 1;
        if (c < 15) stage(buf ^ 1, (c + 1) * 64);   // async, hides under compute
#pragma unroll
        for (int t = 0; t < 2; ++t) {
            const int ks = c * 2 + t;
            short8 afr[4], bfr[4];
#pragma unroll
            for (int fm = 0; fm < 4; ++fm) {
                int row = fm * 16 + l16;
                int cg0 = t * 8 + g * 2;
                int p0 = cg0 ^ (row & 7);
                int p1 = (cg0 + 1) ^ (row & 7);
                f32x4 lo = *reinterpret_cast<const f32x4*>(&As2[buf][row][p0 * 4]);
                f32x4 hi = *reinterpret_cast<const f32x4*>(&As2[buf][row][p1 * 4]);
                short8 a;
                a[0] = (short)f2bf(lo[0]); a[1] = (short)f2bf(lo[1]);
                a[2] = (short)f2bf(lo[2]); a[3] = (short)f2bf(lo[3]);
                a[4] = (short)f2bf(hi[0]); a[5] = (short)f2bf(hi[1]);
                a[6] = (short)f2bf(hi[2]); a[7] = (short)f2bf(hi[3]);
                afr[fm] = a;
            }
#pragma unroll
            for (int fn = 0; fn < 4; ++fn)
                bfr[fn] = Bv[((ks * 4 + wid) * 4 + fn) * 64 + lane];
#pragma unroll
            for (int fm = 0; fm < 4; ++fm)
#pragma unroll
                for (int fn = 0; fn < 4; ++fn)
                    acc[fm][fn] = __builtin_amdgcn_mfma_f32_16x16x32_bf16(
                        afr[fm], bfr[fn], acc[fm][fn], 0, 0, 0);
        }
        __syncthreads();
    }

#pragma unroll
    for (int fm = 0; fm < 4; ++fm) {
#pragma unroll
        for (int r = 0; r < 4; ++r) {
            int row = m0 + fm * 16 + g * 4 + r;
            if (row < M) {
#pragma unroll
                for (int fn = 0; fn < 4; ++fn)
                    P[(size_t)row * 256 + colbase + fn * 16] = f2bf(acc[fm][fn][r]);
            }
        }
    }
}

// ---------- GAT linear via MFMA: single-wave 64-row tiles, no barriers ----------
template <int IND, int KS, int NF, int MODE>
__global__ __launch_bounds__(64) void gat_lin_mfma(
    const float* __restrict__ X, const unsigned short* __restrict__ Bp,
    const float* __restrict__ bl, const float* __restrict__ br,
    float* __restrict__ xl, float* __restrict__ xr, int M)
{
    constexpr int W = KS * 32;
    constexpr int WP = W + 8;
    __shared__ unsigned short xs[64][WP];
    const int lane = threadIdx.x;
    const int m0 = blockIdx.x * 64;
    const int l16 = lane & 15, g = lane >> 4;
    const short8* Bv = reinterpret_cast<const short8*>(Bp);

    constexpr int NV = 64 * IND / 4 / 64;
#pragma unroll
    for (int i = 0; i < NV; ++i) {
        int q = i * 64 + lane;
        int f = q * 4;
        int row = f / IND, col = f % IND;
        int ar = m0 + row;
        float4 v = make_float4(0.f, 0.f, 0.f, 0.f);
        if (ar < M) v = *reinterpret_cast<const float4*>(&X[(size_t)ar * IND + col]);
        ushort4 u;
        u.x = f2bf(v.x); u.y = f2bf(v.y); u.z = f2bf(v.z); u.w = f2bf(v.w);
        *reinterpret_cast<ushort4*>(&xs[row][col]) = u;
    }
    ushort4 zz; zz.x = 0; zz.y = 0; zz.z = 0; zz.w = 0;
#pragma unroll
    for (int c = IND; c < W; c += 4)
        *reinterpret_cast<ushort4*>(&xs[lane][c]) = zz;

    f32x4 acc[4][NF] = {};
#pragma unroll
    for (int t = 0; t < KS; ++t) {
        short8 afr[4], bfr[NF];
#pragma unroll
        for (int fm = 0; fm < 4; ++fm)
            afr[fm] = *reinterpret_cast<const short8*>(&xs[fm * 16 + l16][t * 32 + g * 8]);
#pragma unroll
        for (int fn = 0; fn < NF; ++fn)
            bfr[fn] = Bv[(t * NF + fn) * 64 + lane];
#pragma unroll
        for (int fm = 0; fm < 4; ++fm)
#pragma unroll
            for (int fn = 0; fn < NF; ++fn)
                acc[fm][fn] = __builtin_amdgcn_mfma_f32_16x16x32_bf16(
                    afr[fm], bfr[fn], acc[fm][fn], 0, 0, 0);
    }

#pragma unroll
    for (int fm = 0; fm < 4; ++fm) {
#pragma unroll
        for (int r = 0; r < 4; ++r) {
            int row = m0 + fm * 16 + g * 4 + r;
            if (row < M) {
#pragma unroll
                for (int fn = 0; fn < NF; ++fn) {
                    int col = fn * 16 + l16;
                    float v = acc[fm][fn][r];
                    if (MODE == 1) {
                        if (col < 40) xl[(size_t)row * 40 + col] = v + bl[col];
                        else          xr[(size_t)row * 40 + (col - 40)] = v + br[col - 40];
                    } else {
                        if (col < 20)      xl[(size_t)row * 20 + col] = v + bl[col];
                        else if (col < 40) xr[(size_t)row * 20 + (col - 20)] = v + br[col - 20];
                    }
                }
            }
        }
    }
}

// ---------- MLP head via MFMA (z bf16 + addf direct) ----------
__global__ __launch_bounds__(256) void mlp_mfma(
    const unsigned short* __restrict__ z, const float* __restrict__ addf,
    const unsigned short* __restrict__ Bt1p,
    const float* __restrict__ fc1b, const float* __restrict__ bnfg, const float* __restrict__ bnfb,
    const float* __restrict__ fc2W, const float* __restrict__ fc2b,
    float* __restrict__ out, int M)
{
    __shared__ __align__(16) char smem[64 * 169 * 4];
    unsigned short (*zs)[200] = reinterpret_cast<unsigned short(*)[200]>(smem);
    float (*ts)[169] = reinterpret_cast<float(*)[169]>(smem);
    const int tid = threadIdx.x;
    const int wid = tid >> 6, lane = tid & 63;
    const int m0 = blockIdx.x * 64;
    const int l16 = lane & 15, g = lane >> 4;
    const short8* Bv = reinterpret_cast<const short8*>(Bt1p);

#pragma unroll
    for (int p = 0; p < 13; ++p) {
        int idx = p * 256 + tid;
        if (idx < 3200) {
            int row = idx / 50, c4 = (idx % 50) * 4;
            int ar = m0 + row;
            ushort4 u; u.x = 0; u.y = 0; u.z = 0; u.w = 0;
            if (ar < M) {
                if (c4 < 148) {
                    u = *reinterpret_cast<const ushort4*>(&z[(size_t)ar * 168 + c4]);
                } else if (c4 < 168) {
                    float4 v = *reinterpret_cast<const float4*>(&addf[(size_t)ar * 20 + (c4 - 148)]);
                    u.x = f2bf(v.x); u.y = f2bf(v.y); u.z = f2bf(v.z); u.w = f2bf(v.w);
                }
            }
            *reinterpret_cast<ushort4*>(&zs[row][c4]) = u;
        }
    }
    __syncthreads();

    f32x4 acc[4][4] = {};
    if (wid < 3) {
#pragma unroll
        for (int t = 0; t < 6; ++t) {
            short8 afr[4], bfr[4];
#pragma unroll
            for (int fm = 0; fm < 4; ++fm)
                afr[fm] = *reinterpret_cast<const short8*>(&zs[fm * 16 + l16][t * 32 + g * 8]);
#pragma unroll
            for (int fn = 0; fn < 4; ++fn)
                bfr[fn] = Bv[((t * 3 + wid) * 4 + fn) * 64 + lane];
#pragma unroll
            for (int fm = 0; fm < 4; ++fm)
#pragma unroll
                for (int fn = 0; fn < 4; ++fn)
                    acc[fm][fn] = __builtin_amdgcn_mfma_f32_16x16x32_bf16(
                        afr[fm], bfr[fn], acc[fm][fn], 0, 0, 0);
        }
    }
    __syncthreads();
    if (wid < 3) {
        const int colbase = wid * 64 + l16;
#pragma unroll
        for (int fm = 0; fm < 4; ++fm) {
#pragma unroll
            for (int r = 0; r < 4; ++r) {
                int rr = fm * 16 + g * 4 + r;
#pragma unroll
                for (int fn = 0; fn < 4; ++fn) {
                    int col = colbase + fn * 16;
                    if (col < 168) {
                        float v = acc[fm][fn][r] + fc1b[col];
                        v = v * (bnfg[col] * BN_RSQ) + bnfb[col];
                        ts[rr][col] = fmaxf(v, 0.0f);
                    }
                }
            }
        }
    }
    __syncthreads();
    if (tid < 192) {
        int r = tid & 63, c = tid >> 6;
        float acc2 = fc2b[c];
#pragma unroll 4
        for (int k = 0; k < 168; ++k) acc2 += ts[r][k] * fc2W[k * 3 + c];
        int row = m0 + r;
        if (row < M) out[(size_t)row * 3 + c] = acc2;
    }
}

// ---------- exclusive scans (y-fused for both CSRs) ----------
__global__ void scan1(const int* __restrict__ cnt1, const int* __restrict__ cnt2,
                      int* __restrict__ off1, int* __restrict__ off2,
                      int* __restrict__ bsum1, int* __restrict__ bsum2, int M)
{
    __shared__ int sh[SCAN_B];
    int y = blockIdx.y;
    const int* cnt = y ? cnt2 : cnt1;
    int* excl = y ? off2 : off1;
    int* bsum = y ? bsum2 : bsum1;
    int i = blockIdx.x * SCAN_B + threadIdx.x;
    int v = (i < M) ? cnt[i] + y : 0;
    sh[threadIdx.x] = v;
    __syncthreads();
    for (int o = 1; o < SCAN_B; o <<= 1) {
        int t = (threadIdx.x >= o) ? sh[threadIdx.x - o] : 0;
        __syncthreads();
        sh[threadIdx.x] += t;
        __syncthreads();
    }
    if (i < M) excl[i] = sh[threadIdx.x] - v;
    if (threadIdx.x == SCAN_B - 1) bsum[blockIdx.x] = sh[threadIdx.x];
}

__global__ void scan2(int* __restrict__ bsum1, int* __restrict__ bsum2, int nb)
{
    __shared__ int sh[SCAN_B];
    int* bsum = blockIdx.y ? bsum2 : bsum1;
    int v = ((int)threadIdx.x < nb) ? bsum[threadIdx.x] : 0;
    sh[threadIdx.x] = v;
    __syncthreads();
    for (int o = 1; o < SCAN_B; o <<= 1) {
        int t = (threadIdx.x >= o) ? sh[threadIdx.x - o] : 0;
        __syncthreads();
        sh[threadIdx.x] += t;
        __syncthreads();
    }
    if ((int)threadIdx.x < nb) bsum[threadIdx.x] = sh[threadIdx.x] - v;
}

__global__ void scan3(int* __restrict__ off1, int* __restrict__ off2,
                      const int* __restrict__ bsum1, const int* __restrict__ bsum2,
                      const int* __restrict__ cnt1, const int* __restrict__ cnt2,
                      const float* __restrict__ easum, float* __restrict__ eaext,
                      int E, int M)
{
    int y = blockIdx.y;
    int* off = y ? off2 : off1;
    const int* bsum = y ? bsum2 : bsum1;
    const int* cnt = y ? cnt2 : cnt1;
    int i = blockIdx.x * SCAN_B + threadIdx.x;
    if (i < M) {
        int v = off[i] + bsum[blockIdx.x];
        off[i] = v;
        if (i == M - 1) off[M] = v + cnt[i] + y;   // sentinel
        if (y) eaext[E + i] = easum[i] / fmaxf((float)cnt2[i], 1.0f);
    }
}

// ---------- fused CSR fill ----------
__global__ void fill_both(const int* __restrict__ e1s, const int* __restrict__ e1d,
                          const int* __restrict__ e2d,
                          const int* __restrict__ off1, const int* __restrict__ off2,
                          int* __restrict__ cnt1, int* __restrict__ cnt2,
                          int* __restrict__ srcs1, int* __restrict__ eidx2, int E, int Eext)
{
    int t = blockIdx.x * blockDim.x + threadIdx.x;
    if (t < E) {
        int d = e1d[t];
        int pos = atomicSub(&cnt1[d], 1) - 1;
        srcs1[off1[d] + pos] = e1s[t];
    }
    int t2 = t - E;
    if (t2 >= 0 && t2 < Eext) {
        if (t2 < E) {
            int d = e2d[t2];
            int pos = atomicSub(&cnt2[d], 1) - 1;
            eidx2[off2[d] + pos] = t2;
        } else {
            int nn = t2 - E;
            eidx2[off2[nn + 1] - 1] = t2;   // self-loop takes the last slot
        }
    }
}

// ---------- SAGE gather (bf16 P), fused BN/act epilogue into bf16 z ----------
__global__ void sage_gather(const int* __restrict__ srcs1, const int* __restrict__ off1,
                            const unsigned short* __restrict__ P, const float* __restrict__ bl,
                            const float* __restrict__ bng, const float* __restrict__ bnb,
                            unsigned short* __restrict__ z, int N)
{
    int t = blockIdx.x * blockDim.x + threadIdx.x;
    if (t >= N * 32) return;
    int n = t >> 5, g = t & 31;
    int beg = off1[n], end = off1[n + 1];
    float a0 = 0.f, a1 = 0.f, a2 = 0.f, a3 = 0.f;
    for (int j = beg; j < end; ++j) {
        int s = srcs1[j];
        ushort4 v = *reinterpret_cast<const ushort4*>(&P[(size_t)s * 256 + g * 4]);
        a0 += bf2f(v.x); a1 += bf2f(v.y); a2 += bf2f(v.z); a3 += bf2f(v.w);
    }
    float inv = 1.0f / fmaxf((float)(end - beg), 1.0f);
    ushort4 pr = *reinterpret_cast<const ushort4*>(&P[(size_t)n * 256 + 128 + g * 4]);
    float a4[4] = {a0, a1, a2, a3};
    float p4[4] = {bf2f(pr.x), bf2f(pr.y), bf2f(pr.z), bf2f(pr.w)};
    ushort4 zo;
    unsigned short* zp = reinterpret_cast<unsigned short*>(&zo);
#pragma unroll
    for (int k = 0; k < 4; ++k) {
        int cc = g * 4 + k;
        float x = a4[k] * inv + bl[cc] + p4[k];
        x = x * (bng[cc] * BN_RSQ) + bnb[cc];
        zp[k] = f2bf(lrelu(x, 0.01f));
    }
    *reinterpret_cast<ushort4*>(&z[(size_t)n * 168 + g * 4]) = zo;
}

// ---------- fused GATv2 per (node, head): ONE pass, online softmax ----------
template <int H, int C, int MODE>
__global__ void gat_node(const int* __restrict__ eidx2, const int* __restrict__ off2,
                         const int* __restrict__ e2s, const float* __restrict__ eaext,
                         const float* __restrict__ xl, const float* __restrict__ xr,
                         const float* __restrict__ We, const float* __restrict__ att,
                         const float* __restrict__ b,
                         const float* __restrict__ bng, const float* __restrict__ bnb,
                         void* __restrict__ outv, int E, int N)
{
    int t = blockIdx.x * blockDim.x + threadIdx.x;
    if (t >= N * H) return;
    int n = t / H, h = t % H;

    float xrc[C], atth[C], weh[C];
#pragma unroll
    for (int c = 0; c < C; ++c) {
        xrc[c]  = xr[(size_t)n * (H * C) + h * C + c];
        atth[c] = att[h * C + c];
        weh[c]  = We[h * C + c];
    }

    const int beg = off2[n], end = off2[n + 1];

    float mx = -FLT_MAX, den = 0.0f;
    float accv[C] = {};
    for (int j = beg; j < end; ++j) {
        int e = eidx2[j];
        int s = (e < E) ? e2s[e] : (e - E);
        float ea = eaext[e];
        const float* xls = xl + (size_t)s * (H * C) + h * C;
        float xv[C];
        float lg = 0.0f;
#pragma unroll
        for (int c = 0; c < C; ++c) {
            xv[c] = xls[c];
            float m = xv[c] + xrc[c] + ea * weh[c];
            lg += lrelu(m, 0.2f) * atth[c];
        }
        if (lg > mx) {
            float sc = __expf(mx - lg);
            den *= sc;
#pragma unroll
            for (int c = 0; c < C; ++c) accv[c] *= sc;
            mx = lg;
        }
        float ex = __expf(lg - mx);
        den += ex;
#pragma unroll
        for (int c = 0; c < C; ++c) accv[c] += ex * xv[c];
    }
    float inv = 1.0f / (den + 1e-16f);

#pragma unroll
    for (int c = 0; c < C; ++c) {
        int jch = h * C + c;
        float v = accv[c] * inv + b[jch];
        if (MODE == 1) {
            ((float*)outv)[(size_t)n * (H * C) + jch] = lrelu(v, 0.01f);
        } else {
            v = v * (bng[jch] * BN_RSQ) + bnb[jch];
            ((unsigned short*)outv)[(size_t)n * 168 + 128 + jch] = f2bf(lrelu(v, 0.01f));
        }
    }
}

// ---------- launch ----------
extern "C" void kernel_launch(void* const* d_in, const int* in_sizes, int n_in,
                              void* d_out, int out_size, void* d_ws, size_t ws_size,
                              hipStream_t stream)
{
    const float* features = (const float*)d_in[0];
    const int*   e1       = (const int*)d_in[1];
    const int*   e2       = (const int*)d_in[2];
    const float* ef       = (const float*)d_in[3];
    const float* addf     = (const float*)d_in[4];
    const float* sage_Wl  = (const float*)d_in[5];
    const float* sage_bl  = (const float*)d_in[6];
    const float* sage_Wr  = (const float*)d_in[7];
    const float* g1_Wl = (const float*)d_in[8];
    const float* g1_bl = (const float*)d_in[9];
    const float* g1_Wr = (const float*)d_in[10];
    const float* g1_br = (const float*)d_in[11];
    const float* g1_We = (const float*)d_in[12];
    const float* g1_att = (const float*)d_in[13];
    const float* g1_b = (const float*)d_in[14];
    const float* g2_Wl = (const float*)d_in[15];
    const float* g2_bl = (const float*)d_in[16];
    const float* g2_Wr = (const float*)d_in[17];
    const float* g2_br = (const float*)d_in[18];
    const float* g2_We = (const float*)d_in[19];
    const float* g2_att = (const float*)d_in[20];
    const float* g2_b = (const float*)d_in[21];
    const float* fc1_W = (const float*)d_in[22];
    const float* fc1_b = (const float*)d_in[23];
    const float* fc2_W = (const float*)d_in[24];
    const float* fc2_b = (const float*)d_in[25];
    const float* bnx_g = (const float*)d_in[26];
    const float* bnx_b = (const float*)d_in[27];
    const float* bny_g = (const float*)d_in[28];
    const float* bny_b = (const float*)d_in[29];
    const float* bnf_g = (const float*)d_in[30];
    const float* bnf_b = (const float*)d_in[31];

    const int N = in_sizes[0] / 1024;
    const int E = in_sizes[3];
    const int Eext = E + N;
    const int* e1s = e1, *e1d = e1 + E;
    const int* e2s = e2, *e2d = e2 + E;
    const int nb = (N + SCAN_B - 1) / SCAN_B;

    char* wb = (char*)d_ws;
    size_t off = 0;
    auto takeB = [&](size_t bytes) { char* p = wb + off; off = (off + bytes + 255) & ~(size_t)255; return p; };
    unsigned short* P = (unsigned short*)takeB((size_t)N * 256 * 2);
    unsigned short* z = (unsigned short*)takeB((size_t)N * 168 * 2);
    float* eaext = (float*)takeB((size_t)Eext * 4);
    float* xl1   = (float*)takeB((size_t)N * 40 * 4);
    float* xr1   = (float*)takeB((size_t)N * 40 * 4);
    float* y1    = (float*)takeB((size_t)N * 40 * 4);
    float* xl2   = (float*)takeB((size_t)N * 20 * 4);
    float* xr2   = (float*)takeB((size_t)N * 20 * 4);
    unsigned short* Btp  = (unsigned short*)takeB((size_t)256 * 1024 * 2);
    unsigned short* Bt1p = (unsigned short*)takeB((size_t)36864 * 2);
    unsigned short* Bg1  = (unsigned short*)takeB((size_t)2560 * 2);
    unsigned short* Bg2  = (unsigned short*)takeB((size_t)3072 * 2);
    char* zero_beg = wb + off;
    int* cnt1    = (int*)takeB((size_t)N * 4);
    int* cnt2    = (int*)takeB((size_t)N * 4);
    float* easum = (float*)takeB((size_t)N * 4);
    size_t zero_len = (size_t)((wb + off) - zero_beg);
    int* off1  = (int*)takeB((size_t)(N + 1) * 4);
    int* off2  = (int*)takeB((size_t)(N + 1) * 4);
    int* bsum1 = (int*)takeB(SCAN_B * 4);
    int* bsum2 = (int*)takeB(SCAN_B * 4);
    int* srcs1 = (int*)takeB((size_t)E * 4);
    int* eidx2 = (int*)takeB((size_t)Eext * 4);

    const int B = 256;
    const int n16 = (int)(zero_len / 16);
    zero_ws<<<(n16 + B - 1) / B, B, 0, stream>>>((uint4*)zero_beg, n16);

    const int prep_total = 262144 + 36864 + 2560 + 3072 + E;
    prep_all<<<(prep_total + B - 1) / B, B, 0, stream>>>(
        sage_Wl, sage_Wr, Btp, fc1_W, Bt1p,
        g1_Wl, g1_Wr, Bg1, g2_Wl, g2_Wr, Bg2,
        e1d, e2d, ef, cnt1, cnt2, easum, eaext, E);

    scan1<<<dim3(nb, 2), SCAN_B, 0, stream>>>(cnt1, cnt2, off1, off2, bsum1, bsum2, N);
    scan2<<<dim3(1, 2), SCAN_B, 0, stream>>>(bsum1, bsum2, nb);
    scan3<<<dim3(nb, 2), SCAN_B, 0, stream>>>(off1, off2, bsum1, bsum2, cnt1, cnt2,
                                              easum, eaext, E, N);

    fill_both<<<(E + Eext + B - 1) / B, B, 0, stream>>>(e1s, e1d, e2d, off1, off2,
                                                        cnt1, cnt2, srcs1, eidx2, E, Eext);

    const int mtiles = (N + 63) / 64;
    gemm_sage_mfma<<<mtiles, 256, 0, stream>>>(features, Btp, P, N);
    sage_gather<<<(N * 32 + B - 1) / B, B, 0, stream>>>(srcs1, off1, P, sage_bl, bnx_g, bnx_b, z, N);

    gat_lin_mfma<20, 1, 5, 1><<<mtiles, 64, 0, stream>>>(addf, Bg1, g1_bl, g1_br, xl1, xr1, N);
    gat_node<4, 10, 1><<<(N * 4 + B - 1) / B, B, 0, stream>>>(
        eidx2, off2, e2s, eaext, xl1, xr1, g1_We, g1_att, g1_b,
        nullptr, nullptr, (void*)y1, E, N);

    gat_lin_mfma<40, 2, 3, 2><<<mtiles, 64, 0, stream>>>(y1, Bg2, g2_bl, g2_br, xl2, xr2, N);
    gat_node<4, 5, 2><<<(N * 4 + B - 1) / B, B, 0, stream>>>(
        eidx2, off2, e2s, eaext, xl2, xr2, g2_We, g2_att, g2_b,
        bny_g, bny_b, (void*)z, E, N);

    mlp_mfma<<<mtiles, 256, 0, stream>>>(z, addf, Bt1p, fc1_b, bnf_g, bnf_b, fc2_W, fc2_b,
                                         (float*)d_out, N);
}

// Round 12
// 296.770 us; speedup vs baseline: 1.0206x; 1.0206x over previous
//
#include <hip/hip_runtime.h>
#include <hip/hip_bf16.h>
#include <cfloat>

__device__ __forceinline__ float lrelu(float x, float a) { return x > 0.0f ? x : a * x; }

// fp32 -> bf16 round-to-nearest-even (bit pattern)
__device__ __forceinline__ unsigned short f2bf(float f) {
    unsigned u = __float_as_uint(f);
    unsigned r = (u + 0x7FFFu + ((u >> 16) & 1u)) >> 16;
    return (unsigned short)r;
}
__device__ __forceinline__ float bf2f(unsigned short u) {
    return __uint_as_float((unsigned)u << 16);
}

typedef __attribute__((ext_vector_type(8))) short short8;
typedef __attribute__((ext_vector_type(4))) float f32x4;

#define BN_RSQ 0.99999500003749968750f  // 1/sqrt(1+1e-5)
#define SCAN_B 256

// ---------- fast zero ----------
__global__ void zero_ws(uint4* __restrict__ p, int n16)
{
    int t = blockIdx.x * blockDim.x + threadIdx.x;
    if (t < n16) p[t] = make_uint4(0u, 0u, 0u, 0u);
}

// ---------- fused prep: SAGE W pack + fc1 W pack + GAT lin W packs + edge histogram ----------
__global__ void prep_all(const float* __restrict__ sWl, const float* __restrict__ sWr,
                         unsigned short* __restrict__ Btp,
                         const float* __restrict__ fc1W, unsigned short* __restrict__ Bt1p,
                         const float* __restrict__ g1Wl, const float* __restrict__ g1Wr,
                         unsigned short* __restrict__ Bg1,
                         const float* __restrict__ g2Wl, const float* __restrict__ g2Wr,
                         unsigned short* __restrict__ Bg2,
                         const int* __restrict__ e1d, const int* __restrict__ e2d,
                         const float* __restrict__ ef,
                         int* __restrict__ cnt1, int* __restrict__ cnt2,
                         float* __restrict__ easum, int E)
{
    int idx = blockIdx.x * blockDim.x + threadIdx.x;
    if (idx < 262144) {
        int j = idx & 7, lane = (idx >> 3) & 63, fn = (idx >> 9) & 3, wid = (idx >> 11) & 3, t = idx >> 13;
        int c = wid * 64 + fn * 16 + (lane & 15);
        int k = t * 32 + (lane >> 4) * 8 + j;
        float v = (c < 128) ? sWl[(size_t)k * 128 + c] : sWr[(size_t)k * 128 + (c - 128)];
        Btp[idx] = f2bf(v);
        return;
    }
    idx -= 262144;
    if (idx < 36864) {
        int j = idx & 7, lane = (idx >> 3) & 63, fn = (idx >> 9) & 3, q = idx >> 11;
        int wid = q % 3, t = q / 3;
        int c = wid * 64 + fn * 16 + (lane & 15);
        int k = t * 32 + (lane >> 4) * 8 + j;
        float v = (c < 168 && k < 168) ? fc1W[(size_t)k * 168 + c] : 0.0f;
        Bt1p[idx] = f2bf(v);
        return;
    }
    idx -= 36864;
    if (idx < 2560) {
        int j = idx & 7, lane = (idx >> 3) & 63, fn = idx >> 9;
        int c = fn * 16 + (lane & 15);
        int k = (lane >> 4) * 8 + j;
        float v = 0.0f;
        if (k < 20) v = (c < 40) ? g1Wl[(size_t)k * 40 + c] : g1Wr[(size_t)k * 40 + (c - 40)];
        Bg1[idx] = f2bf(v);
        return;
    }
    idx -= 2560;
    if (idx < 3072) {
        int j = idx & 7, lane = (idx >> 3) & 63, q = idx >> 9;
        int fn = q % 3, t = q / 3;
        int c = fn * 16 + (lane & 15);
        int k = t * 32 + (lane >> 4) * 8 + j;
        float v = 0.0f;
        if (k < 40 && c < 40) v = (c < 20) ? g2Wl[(size_t)k * 20 + c] : g2Wr[(size_t)k * 20 + (c - 20)];
        Bg2[idx] = f2bf(v);
        return;
    }
    idx -= 3072;
    if (idx < E) {
        atomicAdd(&cnt1[e1d[idx]], 1);
        int d2 = e2d[idx];
        atomicAdd(&cnt2[d2], 1);
        atomicAdd(&easum[d2], ef[idx]);
    }
}

// ---------- SAGE GEMM via MFMA (R10/R5 structure: 4 waves, 64x256, 2-deep A prefetch) ----------
__global__ __launch_bounds__(256) void gemm_sage_mfma(
    const float* __restrict__ A, const unsigned short* __restrict__ Btp,
    unsigned short* __restrict__ P, int M)
{
    __shared__ unsigned short As2[2][64][72];
    const int tid = threadIdx.x;
    const int wid = tid >> 6, lane = tid & 63;
    const int m0 = blockIdx.x * 64;
    const int l16 = lane & 15, g = lane >> 4;
    const int colbase = wid * 64 + l16;
    const short8* Bv = reinterpret_cast<const short8*>(Btp);
    const int srow = tid >> 4, scol = (tid & 15) * 4;

    f32x4 acc[4][4] = {};
    float4 rcur[4], rnext[4];

#pragma unroll
    for (int p = 0; p < 4; ++p) {
        int ar = m0 + p * 16 + srow;
        rcur[p] = make_float4(0.f, 0.f, 0.f, 0.f);
        if (ar < M) rcur[p] = *reinterpret_cast<const float4*>(&A[(size_t)ar * 1024 + scol]);
    }
#pragma unroll
    for (int p = 0; p < 4; ++p) {
        ushort4 u;
        u.x = f2bf(rcur[p].x); u.y = f2bf(rcur[p].y); u.z = f2bf(rcur[p].z); u.w = f2bf(rcur[p].w);
        *reinterpret_cast<ushort4*>(&As2[0][p * 16 + srow][scol]) = u;
    }
#pragma unroll
    for (int p = 0; p < 4; ++p) {
        int ar = m0 + p * 16 + srow;
        rcur[p] = make_float4(0.f, 0.f, 0.f, 0.f);
        if (ar < M) rcur[p] = *reinterpret_cast<const float4*>(&A[(size_t)ar * 1024 + 64 + scol]);
    }
    __syncthreads();

    for (int c = 0; c < 16; ++c) {
        const int buf = c & 1;
        if (c < 14) {
            const int k0 = (c + 2) * 64;
#pragma unroll
            for (int p = 0; p < 4; ++p) {
                int ar = m0 + p * 16 + srow;
                rnext[p] = make_float4(0.f, 0.f, 0.f, 0.f);
                if (ar < M) rnext[p] = *reinterpret_cast<const float4*>(&A[(size_t)ar * 1024 + k0 + scol]);
            }
        }
#pragma unroll
        for (int t = 0; t < 2; ++t) {
            const int ks = c * 2 + t;
            short8 afr[4], bfr[4];
#pragma unroll
            for (int fm = 0; fm < 4; ++fm)
                afr[fm] = *reinterpret_cast<const short8*>(&As2[buf][fm * 16 + l16][t * 32 + g * 8]);
#pragma unroll
            for (int fn = 0; fn < 4; ++fn)
                bfr[fn] = Bv[((ks * 4 + wid) * 4 + fn) * 64 + lane];
#pragma unroll
            for (int fm = 0; fm < 4; ++fm)
#pragma unroll
                for (int fn = 0; fn < 4; ++fn)
                    acc[fm][fn] = __builtin_amdgcn_mfma_f32_16x16x32_bf16(
                        afr[fm], bfr[fn], acc[fm][fn], 0, 0, 0);
        }
        if (c < 15) {
#pragma unroll
            for (int p = 0; p < 4; ++p) {
                ushort4 u;
                u.x = f2bf(rcur[p].x); u.y = f2bf(rcur[p].y);
                u.z = f2bf(rcur[p].z); u.w = f2bf(rcur[p].w);
                *reinterpret_cast<ushort4*>(&As2[buf ^ 1][p * 16 + srow][scol]) = u;
            }
        }
        __syncthreads();
#pragma unroll
        for (int p = 0; p < 4; ++p) rcur[p] = rnext[p];
    }

#pragma unroll
    for (int fm = 0; fm < 4; ++fm) {
#pragma unroll
        for (int r = 0; r < 4; ++r) {
            int row = m0 + fm * 16 + g * 4 + r;
            if (row < M) {
#pragma unroll
                for (int fn = 0; fn < 4; ++fn)
                    P[(size_t)row * 256 + colbase + fn * 16] = f2bf(acc[fm][fn][r]);
            }
        }
    }
}

// ---------- GAT linear via MFMA: single-wave 64-row tiles; writes PADDED per-head layout ----------
// MODE 1: C=10,PAD=12: xl/xr[(n*4+h)*12+c].  MODE 2: C=5,PAD=8: xl/xr[(n*4+h)*8+c].
template <int IND, int KS, int NF, int MODE>
__global__ __launch_bounds__(64) void gat_lin_mfma(
    const float* __restrict__ X, const unsigned short* __restrict__ Bp,
    const float* __restrict__ bl, const float* __restrict__ br,
    float* __restrict__ xl, float* __restrict__ xr, int M)
{
    constexpr int W = KS * 32;
    constexpr int WP = W + 8;
    __shared__ unsigned short xs[64][WP];
    const int lane = threadIdx.x;
    const int m0 = blockIdx.x * 64;
    const int l16 = lane & 15, g = lane >> 4;
    const short8* Bv = reinterpret_cast<const short8*>(Bp);

    constexpr int NV = 64 * IND / 4 / 64;
#pragma unroll
    for (int i = 0; i < NV; ++i) {
        int q = i * 64 + lane;
        int f = q * 4;
        int row = f / IND, col = f % IND;
        int ar = m0 + row;
        float4 v = make_float4(0.f, 0.f, 0.f, 0.f);
        if (ar < M) v = *reinterpret_cast<const float4*>(&X[(size_t)ar * IND + col]);
        ushort4 u;
        u.x = f2bf(v.x); u.y = f2bf(v.y); u.z = f2bf(v.z); u.w = f2bf(v.w);
        *reinterpret_cast<ushort4*>(&xs[row][col]) = u;
    }
    ushort4 zz; zz.x = 0; zz.y = 0; zz.z = 0; zz.w = 0;
#pragma unroll
    for (int c = IND; c < W; c += 4)
        *reinterpret_cast<ushort4*>(&xs[lane][c]) = zz;

    f32x4 acc[4][NF] = {};
#pragma unroll
    for (int t = 0; t < KS; ++t) {
        short8 afr[4], bfr[NF];
#pragma unroll
        for (int fm = 0; fm < 4; ++fm)
            afr[fm] = *reinterpret_cast<const short8*>(&xs[fm * 16 + l16][t * 32 + g * 8]);
#pragma unroll
        for (int fn = 0; fn < NF; ++fn)
            bfr[fn] = Bv[(t * NF + fn) * 64 + lane];
#pragma unroll
        for (int fm = 0; fm < 4; ++fm)
#pragma unroll
            for (int fn = 0; fn < NF; ++fn)
                acc[fm][fn] = __builtin_amdgcn_mfma_f32_16x16x32_bf16(
                    afr[fm], bfr[fn], acc[fm][fn], 0, 0, 0);
    }

#pragma unroll
    for (int fm = 0; fm < 4; ++fm) {
#pragma unroll
        for (int r = 0; r < 4; ++r) {
            int row = m0 + fm * 16 + g * 4 + r;
            if (row < M) {
#pragma unroll
                for (int fn = 0; fn < NF; ++fn) {
                    int col = fn * 16 + l16;
                    float v = acc[fm][fn][r];
                    if (MODE == 1) {
                        if (col < 40) {
                            int h = col / 10, c = col % 10;
                            xl[((size_t)row * 4 + h) * 12 + c] = v + bl[col];
                        } else if (col < 80) {
                            int cc = col - 40, h = cc / 10, c = cc % 10;
                            xr[((size_t)row * 4 + h) * 12 + c] = v + br[cc];
                        }
                    } else {
                        if (col < 20) {
                            int h = col / 5, c = col % 5;
                            xl[((size_t)row * 4 + h) * 8 + c] = v + bl[col];
                        } else if (col < 40) {
                            int cc = col - 20, h = cc / 5, c = cc % 5;
                            xr[((size_t)row * 4 + h) * 8 + c] = v + br[cc];
                        }
                    }
                }
            }
        }
    }
}

// ---------- MLP head via MFMA (z bf16 + addf direct) ----------
__global__ __launch_bounds__(256) void mlp_mfma(
    const unsigned short* __restrict__ z, const float* __restrict__ addf,
    const unsigned short* __restrict__ Bt1p,
    const float* __restrict__ fc1b, const float* __restrict__ bnfg, const float* __restrict__ bnfb,
    const float* __restrict__ fc2W, const float* __restrict__ fc2b,
    float* __restrict__ out, int M)
{
    __shared__ __align__(16) char smem[64 * 169 * 4];
    unsigned short (*zs)[200] = reinterpret_cast<unsigned short(*)[200]>(smem);
    float (*ts)[169] = reinterpret_cast<float(*)[169]>(smem);
    const int tid = threadIdx.x;
    const int wid = tid >> 6, lane = tid & 63;
    const int m0 = blockIdx.x * 64;
    const int l16 = lane & 15, g = lane >> 4;
    const short8* Bv = reinterpret_cast<const short8*>(Bt1p);

#pragma unroll
    for (int p = 0; p < 13; ++p) {
        int idx = p * 256 + tid;
        if (idx < 3200) {
            int row = idx / 50, c4 = (idx % 50) * 4;
            int ar = m0 + row;
            ushort4 u; u.x = 0; u.y = 0; u.z = 0; u.w = 0;
            if (ar < M) {
                if (c4 < 148) {
                    u = *reinterpret_cast<const ushort4*>(&z[(size_t)ar * 168 + c4]);
                } else if (c4 < 168) {
                    float4 v = *reinterpret_cast<const float4*>(&addf[(size_t)ar * 20 + (c4 - 148)]);
                    u.x = f2bf(v.x); u.y = f2bf(v.y); u.z = f2bf(v.z); u.w = f2bf(v.w);
                }
            }
            *reinterpret_cast<ushort4*>(&zs[row][c4]) = u;
        }
    }
    __syncthreads();

    f32x4 acc[4][4] = {};
    if (wid < 3) {
#pragma unroll
        for (int t = 0; t < 6; ++t) {
            short8 afr[4], bfr[4];
#pragma unroll
            for (int fm = 0; fm < 4; ++fm)
                afr[fm] = *reinterpret_cast<const short8*>(&zs[fm * 16 + l16][t * 32 + g * 8]);
#pragma unroll
            for (int fn = 0; fn < 4; ++fn)
                bfr[fn] = Bv[((t * 3 + wid) * 4 + fn) * 64 + lane];
#pragma unroll
            for (int fm = 0; fm < 4; ++fm)
#pragma unroll
                for (int fn = 0; fn < 4; ++fn)
                    acc[fm][fn] = __builtin_amdgcn_mfma_f32_16x16x32_bf16(
                        afr[fm], bfr[fn], acc[fm][fn], 0, 0, 0);
        }
    }
    __syncthreads();
    if (wid < 3) {
        const int colbase = wid * 64 + l16;
#pragma unroll
        for (int fm = 0; fm < 4; ++fm) {
#pragma unroll
            for (int r = 0; r < 4; ++r) {
                int rr = fm * 16 + g * 4 + r;
#pragma unroll
                for (int fn = 0; fn < 4; ++fn) {
                    int col = colbase + fn * 16;
                    if (col < 168) {
                        float v = acc[fm][fn][r] + fc1b[col];
                        v = v * (bnfg[col] * BN_RSQ) + bnfb[col];
                        ts[rr][col] = fmaxf(v, 0.0f);
                    }
                }
            }
        }
    }
    __syncthreads();
    if (tid < 192) {
        int r = tid & 63, c = tid >> 6;
        float acc2 = fc2b[c];
#pragma unroll 4
        for (int k = 0; k < 168; ++k) acc2 += ts[r][k] * fc2W[k * 3 + c];
        int row = m0 + r;
        if (row < M) out[(size_t)row * 3 + c] = acc2;
    }
}

// ---------- exclusive scans (y-fused for both CSRs) ----------
__global__ void scan1(const int* __restrict__ cnt1, const int* __restrict__ cnt2,
                      int* __restrict__ off1, int* __restrict__ off2,
                      int* __restrict__ bsum1, int* __restrict__ bsum2, int M)
{
    __shared__ int sh[SCAN_B];
    int y = blockIdx.y;
    const int* cnt = y ? cnt2 : cnt1;
    int* excl = y ? off2 : off1;
    int* bsum = y ? bsum2 : bsum1;
    int i = blockIdx.x * SCAN_B + threadIdx.x;
    int v = (i < M) ? cnt[i] + y : 0;
    sh[threadIdx.x] = v;
    __syncthreads();
    for (int o = 1; o < SCAN_B; o <<= 1) {
        int t = (threadIdx.x >= o) ? sh[threadIdx.x - o] : 0;
        __syncthreads();
        sh[threadIdx.x] += t;
        __syncthreads();
    }
    if (i < M) excl[i] = sh[threadIdx.x] - v;
    if (threadIdx.x == SCAN_B - 1) bsum[blockIdx.x] = sh[threadIdx.x];
}

__global__ void scan2(int* __restrict__ bsum1, int* __restrict__ bsum2, int nb)
{
    __shared__ int sh[SCAN_B];
    int* bsum = blockIdx.y ? bsum2 : bsum1;
    int v = ((int)threadIdx.x < nb) ? bsum[threadIdx.x] : 0;
    sh[threadIdx.x] = v;
    __syncthreads();
    for (int o = 1; o < SCAN_B; o <<= 1) {
        int t = (threadIdx.x >= o) ? sh[threadIdx.x - o] : 0;
        __syncthreads();
        sh[threadIdx.x] += t;
        __syncthreads();
    }
    if ((int)threadIdx.x < nb) bsum[threadIdx.x] = sh[threadIdx.x] - v;
}

__global__ void scan3(int* __restrict__ off1, int* __restrict__ off2,
                      const int* __restrict__ bsum1, const int* __restrict__ bsum2,
                      const int* __restrict__ cnt1, const int* __restrict__ cnt2,
                      const float* __restrict__ easum, float* __restrict__ ealoop, int M)
{
    int y = blockIdx.y;
    int* off = y ? off2 : off1;
    const int* bsum = y ? bsum2 : bsum1;
    const int* cnt = y ? cnt2 : cnt1;
    int i = blockIdx.x * SCAN_B + threadIdx.x;
    if (i < M) {
        int v = off[i] + bsum[blockIdx.x];
        off[i] = v;
        if (i == M - 1) off[M] = v + cnt[i] + y;   // sentinel
        if (y) ealoop[i] = easum[i] / fmaxf((float)cnt2[i], 1.0f);
    }
}

// ---------- fused CSR fill: srcs1 (SAGE) + resolved (src, ea) pairs (GAT) ----------
__global__ void fill_both(const int* __restrict__ e1s, const int* __restrict__ e1d,
                          const int* __restrict__ e2s, const int* __restrict__ e2d,
                          const float* __restrict__ ef, const float* __restrict__ ealoop,
                          const int* __restrict__ off1, const int* __restrict__ off2,
                          int* __restrict__ cnt1, int* __restrict__ cnt2,
                          int* __restrict__ srcs1, int2* __restrict__ se2, int E, int Eext)
{
    int t = blockIdx.x * blockDim.x + threadIdx.x;
    if (t < E) {
        int d = e1d[t];
        int pos = atomicSub(&cnt1[d], 1) - 1;
        srcs1[off1[d] + pos] = e1s[t];
    }
    int t2 = t - E;
    if (t2 >= 0 && t2 < Eext) {
        if (t2 < E) {
            int d = e2d[t2];
            int pos = atomicSub(&cnt2[d], 1) - 1;
            se2[off2[d] + pos] = make_int2(e2s[t2], __float_as_int(ef[t2]));
        } else {
            int nn = t2 - E;
            se2[off2[nn + 1] - 1] = make_int2(nn, __float_as_int(ealoop[nn]));
        }
    }
}

// ---------- SAGE gather (bf16 P, 16B/lane), fused BN/act epilogue into bf16 z ----------
__global__ void sage_gather(const int* __restrict__ srcs1, const int* __restrict__ off1,
                            const unsigned short* __restrict__ P, const float* __restrict__ bl,
                            const float* __restrict__ bng, const float* __restrict__ bnb,
                            unsigned short* __restrict__ z, int N)
{
    int t = blockIdx.x * blockDim.x + threadIdx.x;
    if (t >= N * 16) return;
    int n = t >> 4, g = t & 15;
    int beg = off1[n], end = off1[n + 1];
    float a[8] = {};
    for (int j = beg; j < end; ++j) {
        int s = srcs1[j];
        short8 v = *reinterpret_cast<const short8*>(&P[(size_t)s * 256 + g * 8]);
#pragma unroll
        for (int k = 0; k < 8; ++k) a[k] += bf2f((unsigned short)v[k]);
    }
    float inv = 1.0f / fmaxf((float)(end - beg), 1.0f);
    short8 pr = *reinterpret_cast<const short8*>(&P[(size_t)n * 256 + 128 + g * 8]);
    short8 zo;
#pragma unroll
    for (int k = 0; k < 8; ++k) {
        int cc = g * 8 + k;
        float x = a[k] * inv + bl[cc] + bf2f((unsigned short)pr[k]);
        x = x * (bng[cc] * BN_RSQ) + bnb[cc];
        zo[k] = (short)f2bf(lrelu(x, 0.01f));
    }
    *reinterpret_cast<short8*>(&z[(size_t)n * 168 + g * 8]) = zo;
}

// ---------- fused GATv2 per (node, head): ONE pass, online softmax, vectorized loads ----------
template <int H, int C, int PAD, int MODE>
__global__ void gat_node(const int2* __restrict__ se2, const int* __restrict__ off2,
                         const float* __restrict__ xl, const float* __restrict__ xr,
                         const float* __restrict__ We, const float* __restrict__ att,
                         const float* __restrict__ b,
                         const float* __restrict__ bng, const float* __restrict__ bnb,
                         void* __restrict__ outv, int N)
{
    int t = blockIdx.x * blockDim.x + threadIdx.x;
    if (t >= N * H) return;
    int n = t / H, h = t % H;

    float xrc[PAD], atth[PAD], weh[PAD];
    const float4* xrp = reinterpret_cast<const float4*>(&xr[((size_t)n * H + h) * PAD]);
#pragma unroll
    for (int q = 0; q < PAD / 4; ++q) {
        float4 v = xrp[q];
        xrc[q * 4 + 0] = v.x; xrc[q * 4 + 1] = v.y; xrc[q * 4 + 2] = v.z; xrc[q * 4 + 3] = v.w;
    }
#pragma unroll
    for (int c = 0; c < PAD; ++c) {
        atth[c] = (c < C) ? att[h * C + c] : 0.0f;
        weh[c]  = (c < C) ? We[h * C + c]  : 0.0f;
    }

    const int beg = off2[n], end = off2[n + 1];

    float mx = -FLT_MAX, den = 0.0f;
    float accv[PAD] = {};
    for (int j = beg; j < end; ++j) {
        int2 se = se2[j];
        int s = se.x;
        float ea = __int_as_float(se.y);
        const float4* xlp = reinterpret_cast<const float4*>(&xl[((size_t)s * H + h) * PAD]);
        float xv[PAD];
#pragma unroll
        for (int q = 0; q < PAD / 4; ++q) {
            float4 v = xlp[q];
            xv[q * 4 + 0] = v.x; xv[q * 4 + 1] = v.y; xv[q * 4 + 2] = v.z; xv[q * 4 + 3] = v.w;
        }
        float lg = 0.0f;
#pragma unroll
        for (int c = 0; c < PAD; ++c) {
            float m = xv[c] + xrc[c] + ea * weh[c];
            lg += lrelu(m, 0.2f) * atth[c];
        }
        if (lg > mx) {
            float sc = __expf(mx - lg);
            den *= sc;
#pragma unroll
            for (int c = 0; c < PAD; ++c) accv[c] *= sc;
            mx = lg;
        }
        float ex = __expf(lg - mx);
        den += ex;
#pragma unroll
        for (int c = 0; c < PAD; ++c) accv[c] += ex * xv[c];
    }
    float inv = 1.0f / (den + 1e-16f);

#pragma unroll
    for (int c = 0; c < C; ++c) {
        int jch = h * C + c;
        float v = accv[c] * inv + b[jch];
        if (MODE == 1) {
            ((float*)outv)[(size_t)n * (H * C) + jch] = lrelu(v, 0.01f);
        } else {
            v = v * (bng[jch] * BN_RSQ) + bnb[jch];
            ((unsigned short*)outv)[(size_t)n * 168 + 128 + jch] = f2bf(lrelu(v, 0.01f));
        }
    }
}

// ---------- launch ----------
extern "C" void kernel_launch(void* const* d_in, const int* in_sizes, int n_in,
                              void* d_out, int out_size, void* d_ws, size_t ws_size,
                              hipStream_t stream)
{
    const float* features = (const float*)d_in[0];
    const int*   e1       = (const int*)d_in[1];
    const int*   e2       = (const int*)d_in[2];
    const float* ef       = (const float*)d_in[3];
    const float* addf     = (const float*)d_in[4];
    const float* sage_Wl  = (const float*)d_in[5];
    const float* sage_bl  = (const float*)d_in[6];
    const float* sage_Wr  = (const float*)d_in[7];
    const float* g1_Wl = (const float*)d_in[8];
    const float* g1_bl = (const float*)d_in[9];
    const float* g1_Wr = (const float*)d_in[10];
    const float* g1_br = (const float*)d_in[11];
    const float* g1_We = (const float*)d_in[12];
    const float* g1_att = (const float*)d_in[13];
    const float* g1_b = (const float*)d_in[14];
    const float* g2_Wl = (const float*)d_in[15];
    const float* g2_bl = (const float*)d_in[16];
    const float* g2_Wr = (const float*)d_in[17];
    const float* g2_br = (const float*)d_in[18];
    const float* g2_We = (const float*)d_in[19];
    const float* g2_att = (const float*)d_in[20];
    const float* g2_b = (const float*)d_in[21];
    const float* fc1_W = (const float*)d_in[22];
    const float* fc1_b = (const float*)d_in[23];
    const float* fc2_W = (const float*)d_in[24];
    const float* fc2_b = (const float*)d_in[25];
    const float* bnx_g = (const float*)d_in[26];
    const float* bnx_b = (const float*)d_in[27];
    const float* bny_g = (const float*)d_in[28];
    const float* bny_b = (const float*)d_in[29];
    const float* bnf_g = (const float*)d_in[30];
    const float* bnf_b = (const float*)d_in[31];

    const int N = in_sizes[0] / 1024;
    const int E = in_sizes[3];
    const int Eext = E + N;
    const int* e1s = e1, *e1d = e1 + E;
    const int* e2s = e2, *e2d = e2 + E;
    const int nb = (N + SCAN_B - 1) / SCAN_B;

    char* wb = (char*)d_ws;
    size_t off = 0;
    auto takeB = [&](size_t bytes) { char* p = wb + off; off = (off + bytes + 255) & ~(size_t)255; return p; };
    unsigned short* P = (unsigned short*)takeB((size_t)N * 256 * 2);
    unsigned short* z = (unsigned short*)takeB((size_t)N * 168 * 2);
    float* ealoop = (float*)takeB((size_t)N * 4);
    float* xl1   = (float*)takeB((size_t)N * 48 * 4);
    float* xr1   = (float*)takeB((size_t)N * 48 * 4);
    float* y1    = (float*)takeB((size_t)N * 40 * 4);
    float* xl2   = (float*)takeB((size_t)N * 32 * 4);
    float* xr2   = (float*)takeB((size_t)N * 32 * 4);
    unsigned short* Btp  = (unsigned short*)takeB((size_t)256 * 1024 * 2);
    unsigned short* Bt1p = (unsigned short*)takeB((size_t)36864 * 2);
    unsigned short* Bg1  = (unsigned short*)takeB((size_t)2560 * 2);
    unsigned short* Bg2  = (unsigned short*)takeB((size_t)3072 * 2);
    char* zero_beg = wb + off;
    int* cnt1    = (int*)takeB((size_t)N * 4);
    int* cnt2    = (int*)takeB((size_t)N * 4);
    float* easum = (float*)takeB((size_t)N * 4);
    size_t zero_len = (size_t)((wb + off) - zero_beg);
    int* off1  = (int*)takeB((size_t)(N + 1) * 4);
    int* off2  = (int*)takeB((size_t)(N + 1) * 4);
    int* bsum1 = (int*)takeB(SCAN_B * 4);
    int* bsum2 = (int*)takeB(SCAN_B * 4);
    int* srcs1 = (int*)takeB((size_t)E * 4);
    int2* se2  = (int2*)takeB((size_t)Eext * 8);

    const int B = 256;
    const int n16 = (int)(zero_len / 16);
    zero_ws<<<(n16 + B - 1) / B, B, 0, stream>>>((uint4*)zero_beg, n16);

    const int prep_total = 262144 + 36864 + 2560 + 3072 + E;
    prep_all<<<(prep_total + B - 1) / B, B, 0, stream>>>(
        sage_Wl, sage_Wr, Btp, fc1_W, Bt1p,
        g1_Wl, g1_Wr, Bg1, g2_Wl, g2_Wr, Bg2,
        e1d, e2d, ef, cnt1, cnt2, easum, E);

    scan1<<<dim3(nb, 2), SCAN_B, 0, stream>>>(cnt1, cnt2, off1, off2, bsum1, bsum2, N);
    scan2<<<dim3(1, 2), SCAN_B, 0, stream>>>(bsum1, bsum2, nb);
    scan3<<<dim3(nb, 2), SCAN_B, 0, stream>>>(off1, off2, bsum1, bsum2, cnt1, cnt2,
                                              easum, ealoop, N);

    fill_both<<<(E + Eext + B - 1) / B, B, 0, stream>>>(e1s, e1d, e2s, e2d, ef, ealoop,
                                                        off1, off2, cnt1, cnt2,
                                                        srcs1, se2, E, Eext);

    const int mtiles = (N + 63) / 64;
    gemm_sage_mfma<<<mtiles, 256, 0, stream>>>(features, Btp, P, N);
    sage_gather<<<(N * 16 + B - 1) / B, B, 0, stream>>>(srcs1, off1, P, sage_bl, bnx_g, bnx_b, z, N);

    gat_lin_mfma<20, 1, 5, 1><<<mtiles, 64, 0, stream>>>(addf, Bg1, g1_bl, g1_br, xl1, xr1, N);
    gat_node<4, 10, 12, 1><<<(N * 4 + B - 1) / B, B, 0, stream>>>(
        se2, off2, xl1, xr1, g1_We, g1_att, g1_b, nullptr, nullptr, (void*)y1, N);

    gat_lin_mfma<40, 2, 3, 2><<<mtiles, 64, 0, stream>>>(y1, Bg2, g2_bl, g2_br, xl2, xr2, N);
    gat_node<4, 5, 8, 2><<<(N * 4 + B - 1) / B, B, 0, stream>>>(
        se2, off2, xl2, xr2, g2_We, g2_att, g2_b, bny_g, bny_b, (void*)z, N);

    mlp_mfma<<<mtiles, 256, 0, stream>>>(z, addf, Bt1p, fc1_b, bnf_g, bnf_b, fc2_W, fc2_b,
                                         (float*)d_out, N);
}

// Round 14
// 260.550 us; speedup vs baseline: 1.1624x; 1.1390x over previous
//
#include <hip/hip_runtime.h>
#include <hip/hip_bf16.h>
#include <cfloat>

__device__ __forceinline__ float lrelu(float x, float a) { return x > 0.0f ? x : a * x; }

__device__ __forceinline__ unsigned short f2bf(float f) {
    unsigned u = __float_as_uint(f);
    unsigned r = (u + 0x7FFFu + ((u >> 16) & 1u)) >> 16;
    return (unsigned short)r;
}
__device__ __forceinline__ float bf2f(unsigned short u) {
    return __uint_as_float((unsigned)u << 16);
}

typedef __attribute__((ext_vector_type(8))) short short8;
typedef __attribute__((ext_vector_type(4))) float f32x4;

#define BN_RSQ 0.99999500003749968750f
#define SCAN_B 256

// ---------- fast zero ----------
__global__ void zero_ws(uint4* __restrict__ p, int n16)
{
    int t = blockIdx.x * blockDim.x + threadIdx.x;
    if (t < n16) p[t] = make_uint4(0u, 0u, 0u, 0u);
}

// ---------- fused prep ----------
__global__ void prep_all(const float* __restrict__ sWl, const float* __restrict__ sWr,
                         unsigned short* __restrict__ Btp,
                         const float* __restrict__ fc1W, unsigned short* __restrict__ Bt1p,
                         const float* __restrict__ g1Wl, const float* __restrict__ g1Wr,
                         unsigned short* __restrict__ Bg1,
                         const float* __restrict__ g2Wl, const float* __restrict__ g2Wr,
                         unsigned short* __restrict__ Bg2,
                         const int* __restrict__ e1d, const int* __restrict__ e2d,
                         const float* __restrict__ ef,
                         int* __restrict__ cnt1, int* __restrict__ cnt2,
                         float* __restrict__ easum, int E)
{
    int idx = blockIdx.x * blockDim.x + threadIdx.x;
    if (idx < 262144) {
        int j = idx & 7, lane = (idx >> 3) & 63, fn = (idx >> 9) & 3, wid = (idx >> 11) & 3, t = idx >> 13;
        int c = wid * 64 + fn * 16 + (lane & 15);
        int k = t * 32 + (lane >> 4) * 8 + j;
        float v = (c < 128) ? sWl[(size_t)k * 128 + c] : sWr[(size_t)k * 128 + (c - 128)];
        Btp[idx] = f2bf(v);
        return;
    }
    idx -= 262144;
    if (idx < 36864) {
        int j = idx & 7, lane = (idx >> 3) & 63, fn = (idx >> 9) & 3, q = idx >> 11;
        int wid = q % 3, t = q / 3;
        int c = wid * 64 + fn * 16 + (lane & 15);
        int k = t * 32 + (lane >> 4) * 8 + j;
        float v = (c < 168 && k < 168) ? fc1W[(size_t)k * 168 + c] : 0.0f;
        Bt1p[idx] = f2bf(v);
        return;
    }
    idx -= 36864;
    if (idx < 2560) {
        int j = idx & 7, lane = (idx >> 3) & 63, fn = idx >> 9;
        int c = fn * 16 + (lane & 15);
        int k = (lane >> 4) * 8 + j;
        float v = 0.0f;
        if (k < 20) v = (c < 40) ? g1Wl[(size_t)k * 40 + c] : g1Wr[(size_t)k * 40 + (c - 40)];
        Bg1[idx] = f2bf(v);
        return;
    }
    idx -= 2560;
    if (idx < 3072) {
        int j = idx & 7, lane = (idx >> 3) & 63, q = idx >> 9;
        int fn = q % 3, t = q / 3;
        int c = fn * 16 + (lane & 15);
        int k = t * 32 + (lane >> 4) * 8 + j;
        float v = 0.0f;
        if (k < 40 && c < 40) v = (c < 20) ? g2Wl[(size_t)k * 20 + c] : g2Wr[(size_t)k * 20 + (c - 20)];
        Bg2[idx] = f2bf(v);
        return;
    }
    idx -= 3072;
    if (idx < E) {
        atomicAdd(&cnt1[e1d[idx]], 1);
        int d2 = e2d[idx];
        atomicAdd(&cnt2[d2], 1);
        atomicAdd(&easum[d2], ef[idx]);
    }
}

// ---------- exclusive scans ----------
__global__ void scan1(const int* __restrict__ cnt1, const int* __restrict__ cnt2,
                      int* __restrict__ off1, int* __restrict__ off2,
                      int* __restrict__ bsum1, int* __restrict__ bsum2, int M)
{
    __shared__ int sh[SCAN_B];
    int y = blockIdx.y;
    const int* cnt = y ? cnt2 : cnt1;
    int* excl = y ? off2 : off1;
    int* bsum = y ? bsum2 : bsum1;
    int i = blockIdx.x * SCAN_B + threadIdx.x;
    int v = (i < M) ? cnt[i] + y : 0;
    sh[threadIdx.x] = v;
    __syncthreads();
    for (int o = 1; o < SCAN_B; o <<= 1) {
        int t = (threadIdx.x >= o) ? sh[threadIdx.x - o] : 0;
        __syncthreads();
        sh[threadIdx.x] += t;
        __syncthreads();
    }
    if (i < M) excl[i] = sh[threadIdx.x] - v;
    if (threadIdx.x == SCAN_B - 1) bsum[blockIdx.x] = sh[threadIdx.x];
}

__global__ void scan2(int* __restrict__ bsum1, int* __restrict__ bsum2, int nb)
{
    __shared__ int sh[SCAN_B];
    int* bsum = blockIdx.y ? bsum2 : bsum1;
    int v = ((int)threadIdx.x < nb) ? bsum[threadIdx.x] : 0;
    sh[threadIdx.x] = v;
    __syncthreads();
    for (int o = 1; o < SCAN_B; o <<= 1) {
        int t = (threadIdx.x >= o) ? sh[threadIdx.x - o] : 0;
        __syncthreads();
        sh[threadIdx.x] += t;
        __syncthreads();
    }
    if ((int)threadIdx.x < nb) bsum[threadIdx.x] = sh[threadIdx.x] - v;
}

__global__ void scan3(int* __restrict__ off1, int* __restrict__ off2,
                      const int* __restrict__ bsum1, const int* __restrict__ bsum2,
                      const int* __restrict__ cnt1, const int* __restrict__ cnt2,
                      const float* __restrict__ easum, float* __restrict__ ealoop, int M)
{
    int y = blockIdx.y;
    int* off = y ? off2 : off1;
    const int* bsum = y ? bsum2 : bsum1;
    const int* cnt = y ? cnt2 : cnt1;
    int i = blockIdx.x * SCAN_B + threadIdx.x;
    if (i < M) {
        int v = off[i] + bsum[blockIdx.x];
        off[i] = v;
        if (i == M - 1) off[M] = v + cnt[i] + y;
        if (y) ealoop[i] = easum[i] / fmaxf((float)cnt2[i], 1.0f);
    }
}

// ---------- stageA: gemm (blocks [0,Gg)) || CSR fill (next Gf) || GAT1 lin (rest) ----------
__global__ __launch_bounds__(256) void stageA(
    const float* __restrict__ A, const unsigned short* __restrict__ Btp,
    unsigned short* __restrict__ P,
    const int* __restrict__ e1s, const int* __restrict__ e1d,
    const int* __restrict__ e2s, const int* __restrict__ e2d,
    const float* __restrict__ ef, const float* __restrict__ ealoop,
    const int* __restrict__ off1, const int* __restrict__ off2,
    int* __restrict__ cnt1, int* __restrict__ cnt2,
    int* __restrict__ srcs1, int2* __restrict__ se2,
    const float* __restrict__ addf, const unsigned short* __restrict__ Bg1,
    const float* __restrict__ g1bl, const float* __restrict__ g1br,
    unsigned short* __restrict__ xl1b, unsigned short* __restrict__ xr1b,
    int M, int E, int Eext, int Gg, int Gf)
{
    __shared__ __align__(16) char smem[20480];
    const int bid = blockIdx.x;
    const int tid = threadIdx.x;

    if (bid < Gg) {
        // ===== GEMM path (R10 structure) =====
        typedef unsigned short As2_t[64][72];
        As2_t* As2 = reinterpret_cast<As2_t*>(smem);
        const int wid = tid >> 6, lane = tid & 63;
        const int m0 = bid * 64;
        const int l16 = lane & 15, g = lane >> 4;
        const int colbase = wid * 64 + l16;
        const short8* Bv = reinterpret_cast<const short8*>(Btp);
        const int srow = tid >> 4, scol = (tid & 15) * 4;

        f32x4 acc[4][4] = {};
        float4 rcur[4], rnext[4];

#pragma unroll
        for (int p = 0; p < 4; ++p) {
            int ar = m0 + p * 16 + srow;
            rcur[p] = make_float4(0.f, 0.f, 0.f, 0.f);
            if (ar < M) rcur[p] = *reinterpret_cast<const float4*>(&A[(size_t)ar * 1024 + scol]);
        }
#pragma unroll
        for (int p = 0; p < 4; ++p) {
            ushort4 u;
            u.x = f2bf(rcur[p].x); u.y = f2bf(rcur[p].y); u.z = f2bf(rcur[p].z); u.w = f2bf(rcur[p].w);
            *reinterpret_cast<ushort4*>(&As2[0][p * 16 + srow][scol]) = u;
        }
#pragma unroll
        for (int p = 0; p < 4; ++p) {
            int ar = m0 + p * 16 + srow;
            rcur[p] = make_float4(0.f, 0.f, 0.f, 0.f);
            if (ar < M) rcur[p] = *reinterpret_cast<const float4*>(&A[(size_t)ar * 1024 + 64 + scol]);
        }
        __syncthreads();

        for (int c = 0; c < 16; ++c) {
            const int buf = c & 1;
            if (c < 14) {
                const int k0 = (c + 2) * 64;
#pragma unroll
                for (int p = 0; p < 4; ++p) {
                    int ar = m0 + p * 16 + srow;
                    rnext[p] = make_float4(0.f, 0.f, 0.f, 0.f);
                    if (ar < M) rnext[p] = *reinterpret_cast<const float4*>(&A[(size_t)ar * 1024 + k0 + scol]);
                }
            }
#pragma unroll
            for (int t = 0; t < 2; ++t) {
                const int ks = c * 2 + t;
                short8 afr[4], bfr[4];
#pragma unroll
                for (int fm = 0; fm < 4; ++fm)
                    afr[fm] = *reinterpret_cast<const short8*>(&As2[buf][fm * 16 + l16][t * 32 + g * 8]);
#pragma unroll
                for (int fn = 0; fn < 4; ++fn)
                    bfr[fn] = Bv[((ks * 4 + wid) * 4 + fn) * 64 + lane];
#pragma unroll
                for (int fm = 0; fm < 4; ++fm)
#pragma unroll
                    for (int fn = 0; fn < 4; ++fn)
                        acc[fm][fn] = __builtin_amdgcn_mfma_f32_16x16x32_bf16(
                            afr[fm], bfr[fn], acc[fm][fn], 0, 0, 0);
            }
            if (c < 15) {
#pragma unroll
                for (int p = 0; p < 4; ++p) {
                    ushort4 u;
                    u.x = f2bf(rcur[p].x); u.y = f2bf(rcur[p].y);
                    u.z = f2bf(rcur[p].z); u.w = f2bf(rcur[p].w);
                    *reinterpret_cast<ushort4*>(&As2[buf ^ 1][p * 16 + srow][scol]) = u;
                }
            }
            __syncthreads();
#pragma unroll
            for (int p = 0; p < 4; ++p) rcur[p] = rnext[p];
        }

#pragma unroll
        for (int fm = 0; fm < 4; ++fm) {
#pragma unroll
            for (int r = 0; r < 4; ++r) {
                int row = m0 + fm * 16 + g * 4 + r;
                if (row < M) {
#pragma unroll
                    for (int fn = 0; fn < 4; ++fn)
                        P[(size_t)row * 256 + colbase + fn * 16] = f2bf(acc[fm][fn][r]);
                }
            }
        }
    } else if (bid < Gg + Gf) {
        // ===== CSR fill path =====
        int t = (bid - Gg) * 256 + tid;
        if (t < E) {
            int d = e1d[t];
            int pos = atomicSub(&cnt1[d], 1) - 1;
            srcs1[off1[d] + pos] = e1s[t];
        }
        int t2 = t - E;
        if (t2 >= 0 && t2 < Eext) {
            if (t2 < E) {
                int d = e2d[t2];
                int pos = atomicSub(&cnt2[d], 1) - 1;
                se2[off2[d] + pos] = make_int2(e2s[t2], __float_as_int(ef[t2]));
            } else {
                int nn = t2 - E;
                se2[off2[nn + 1] - 1] = make_int2(nn, __float_as_int(ealoop[nn]));
            }
        }
    } else {
        // ===== GAT1 linear path: 4 waves, each one 64-row tile; bf16 out, PAD=16 =====
        const int wid = tid >> 6, lane = tid & 63;
        const int tile = (bid - Gg - Gf) * 4 + wid;
        const int m0 = tile * 64;
        if (m0 >= M) return;
        unsigned short (*xs)[40] = reinterpret_cast<unsigned short(*)[40]>(smem + wid * 5120);
        const int l16 = lane & 15, g = lane >> 4;
        const short8* Bv = reinterpret_cast<const short8*>(Bg1);

#pragma unroll
        for (int i = 0; i < 5; ++i) {
            int q = i * 64 + lane;
            int f = q * 4;
            int row = f / 20, col = f % 20;
            int ar = m0 + row;
            float4 v = make_float4(0.f, 0.f, 0.f, 0.f);
            if (ar < M) v = *reinterpret_cast<const float4*>(&addf[(size_t)ar * 20 + col]);
            ushort4 u;
            u.x = f2bf(v.x); u.y = f2bf(v.y); u.z = f2bf(v.z); u.w = f2bf(v.w);
            *reinterpret_cast<ushort4*>(&xs[row][col]) = u;
        }
        ushort4 zz; zz.x = 0; zz.y = 0; zz.z = 0; zz.w = 0;
#pragma unroll
        for (int c = 20; c < 32; c += 4)
            *reinterpret_cast<ushort4*>(&xs[lane][c]) = zz;

        f32x4 acc[4][5] = {};
        short8 afr[4], bfr[5];
#pragma unroll
        for (int fm = 0; fm < 4; ++fm)
            afr[fm] = *reinterpret_cast<const short8*>(&xs[fm * 16 + l16][g * 8]);
#pragma unroll
        for (int fn = 0; fn < 5; ++fn)
            bfr[fn] = Bv[fn * 64 + lane];
#pragma unroll
        for (int fm = 0; fm < 4; ++fm)
#pragma unroll
            for (int fn = 0; fn < 5; ++fn)
                acc[fm][fn] = __builtin_amdgcn_mfma_f32_16x16x32_bf16(
                    afr[fm], bfr[fn], acc[fm][fn], 0, 0, 0);

#pragma unroll
        for (int fm = 0; fm < 4; ++fm) {
#pragma unroll
            for (int r = 0; r < 4; ++r) {
                int row = m0 + fm * 16 + g * 4 + r;
                if (row < M) {
#pragma unroll
                    for (int fn = 0; fn < 5; ++fn) {
                        int col = fn * 16 + l16;
                        float v = acc[fm][fn][r];
                        if (col < 40) {
                            int h = col / 10, c = col % 10;
                            xl1b[((size_t)row * 4 + h) * 16 + c] = f2bf(v + g1bl[col]);
                        } else if (col < 80) {
                            int cc = col - 40, h = cc / 10, c = cc % 10;
                            xr1b[((size_t)row * 4 + h) * 16 + c] = f2bf(v + g1br[cc]);
                        }
                    }
                }
            }
        }
    }
}

// ---------- fused GATv2 node core (device helper): ONE pass, online softmax, bf16 xl/xr ----------
template <int H, int C, int BPAD, int MODE>
__device__ __forceinline__ void gat_node_core(
    const int2* __restrict__ se2, const int* __restrict__ off2,
    const unsigned short* __restrict__ xlb, const unsigned short* __restrict__ xrb,
    const float* __restrict__ We, const float* __restrict__ att,
    const float* __restrict__ b,
    const float* __restrict__ bng, const float* __restrict__ bnb,
    void* __restrict__ outv, int n, int h)
{
    float xrc[C], atth[C], weh[C];
    {
        short8 sv[BPAD / 8];
#pragma unroll
        for (int q = 0; q < BPAD / 8; ++q)
            sv[q] = *reinterpret_cast<const short8*>(&xrb[((size_t)n * H + h) * BPAD + q * 8]);
#pragma unroll
        for (int c = 0; c < C; ++c) xrc[c] = bf2f((unsigned short)sv[c / 8][c % 8]);
    }
#pragma unroll
    for (int c = 0; c < C; ++c) {
        atth[c] = att[h * C + c];
        weh[c]  = We[h * C + c];
    }

    const int beg = off2[n], end = off2[n + 1];
    float mx = -FLT_MAX, den = 0.0f;
    float accv[C] = {};
    for (int j = beg; j < end; ++j) {
        int2 se = se2[j];
        int s = se.x;
        float ea = __int_as_float(se.y);
        short8 sv[BPAD / 8];
#pragma unroll
        for (int q = 0; q < BPAD / 8; ++q)
            sv[q] = *reinterpret_cast<const short8*>(&xlb[((size_t)s * H + h) * BPAD + q * 8]);
        float xv[C];
        float lg = 0.0f;
#pragma unroll
        for (int c = 0; c < C; ++c) {
            xv[c] = bf2f((unsigned short)sv[c / 8][c % 8]);
            float m = xv[c] + xrc[c] + ea * weh[c];
            lg += lrelu(m, 0.2f) * atth[c];
        }
        if (lg > mx) {
            float sc = __expf(mx - lg);
            den *= sc;
#pragma unroll
            for (int c = 0; c < C; ++c) accv[c] *= sc;
            mx = lg;
        }
        float ex = __expf(lg - mx);
        den += ex;
#pragma unroll
        for (int c = 0; c < C; ++c) accv[c] += ex * xv[c];
    }
    float inv = 1.0f / (den + 1e-16f);

#pragma unroll
    for (int c = 0; c < C; ++c) {
        int jch = h * C + c;
        float v = accv[c] * inv + b[jch];
        if (MODE == 1) {
            ((float*)outv)[(size_t)n * (H * C) + jch] = lrelu(v, 0.01f);
        } else {
            v = v * (bng[jch] * BN_RSQ) + bnb[jch];
            ((unsigned short*)outv)[(size_t)n * 168 + 128 + jch] = f2bf(lrelu(v, 0.01f));
        }
    }
}

// ---------- stageB: sage_gather (blocks [0,Gg)) || gat_node layer1 (rest) ----------
__global__ void stageB(const int* __restrict__ srcs1, const int* __restrict__ off1,
                       const unsigned short* __restrict__ P, const float* __restrict__ bl,
                       const float* __restrict__ bng, const float* __restrict__ bnb,
                       unsigned short* __restrict__ z,
                       const int2* __restrict__ se2, const int* __restrict__ off2,
                       const unsigned short* __restrict__ xl1b, const unsigned short* __restrict__ xr1b,
                       const float* __restrict__ g1We, const float* __restrict__ g1att,
                       const float* __restrict__ g1b, float* __restrict__ y1,
                       int N, int Gg)
{
    const int bid = blockIdx.x;
    if (bid < Gg) {
        int t = bid * 256 + threadIdx.x;
        if (t >= N * 16) return;
        int n = t >> 4, g = t & 15;
        int beg = off1[n], end = off1[n + 1];
        float a[8] = {};
        for (int j = beg; j < end; ++j) {
            int s = srcs1[j];
            short8 v = *reinterpret_cast<const short8*>(&P[(size_t)s * 256 + g * 8]);
#pragma unroll
            for (int k = 0; k < 8; ++k) a[k] += bf2f((unsigned short)v[k]);
        }
        float inv = 1.0f / fmaxf((float)(end - beg), 1.0f);
        short8 pr = *reinterpret_cast<const short8*>(&P[(size_t)n * 256 + 128 + g * 8]);
        short8 zo;
#pragma unroll
        for (int k = 0; k < 8; ++k) {
            int cc = g * 8 + k;
            float x = a[k] * inv + bl[cc] + bf2f((unsigned short)pr[k]);
            x = x * (bng[cc] * BN_RSQ) + bnb[cc];
            zo[k] = (short)f2bf(lrelu(x, 0.01f));
        }
        *reinterpret_cast<short8*>(&z[(size_t)n * 168 + g * 8]) = zo;
    } else {
        int t = (bid - Gg) * 256 + threadIdx.x;
        if (t >= N * 4) return;
        gat_node_core<4, 10, 16, 1>(se2, off2, xl1b, xr1b, g1We, g1att, g1b,
                                    nullptr, nullptr, (void*)y1, t >> 2, t & 3);
    }
}

// ---------- GAT2 linear via MFMA: single-wave, bf16 out PAD=8 ----------
__global__ __launch_bounds__(64) void gat_lin2_mfma(
    const float* __restrict__ X, const unsigned short* __restrict__ Bp,
    const float* __restrict__ bl, const float* __restrict__ br,
    unsigned short* __restrict__ xlb, unsigned short* __restrict__ xrb, int M)
{
    __shared__ unsigned short xs[64][72];
    const int lane = threadIdx.x;
    const int m0 = blockIdx.x * 64;
    const int l16 = lane & 15, g = lane >> 4;
    const short8* Bv = reinterpret_cast<const short8*>(Bp);

#pragma unroll
    for (int i = 0; i < 10; ++i) {
        int q = i * 64 + lane;
        int f = q * 4;
        int row = f / 40, col = f % 40;
        int ar = m0 + row;
        float4 v = make_float4(0.f, 0.f, 0.f, 0.f);
        if (ar < M) v = *reinterpret_cast<const float4*>(&X[(size_t)ar * 40 + col]);
        ushort4 u;
        u.x = f2bf(v.x); u.y = f2bf(v.y); u.z = f2bf(v.z); u.w = f2bf(v.w);
        *reinterpret_cast<ushort4*>(&xs[row][col]) = u;
    }
    ushort4 zz; zz.x = 0; zz.y = 0; zz.z = 0; zz.w = 0;
#pragma unroll
    for (int c = 40; c < 64; c += 4)
        *reinterpret_cast<ushort4*>(&xs[lane][c]) = zz;

    f32x4 acc[4][3] = {};
#pragma unroll
    for (int t = 0; t < 2; ++t) {
        short8 afr[4], bfr[3];
#pragma unroll
        for (int fm = 0; fm < 4; ++fm)
            afr[fm] = *reinterpret_cast<const short8*>(&xs[fm * 16 + l16][t * 32 + g * 8]);
#pragma unroll
        for (int fn = 0; fn < 3; ++fn)
            bfr[fn] = Bv[(t * 3 + fn) * 64 + lane];
#pragma unroll
        for (int fm = 0; fm < 4; ++fm)
#pragma unroll
            for (int fn = 0; fn < 3; ++fn)
                acc[fm][fn] = __builtin_amdgcn_mfma_f32_16x16x32_bf16(
                    afr[fm], bfr[fn], acc[fm][fn], 0, 0, 0);
    }

#pragma unroll
    for (int fm = 0; fm < 4; ++fm) {
#pragma unroll
        for (int r = 0; r < 4; ++r) {
            int row = m0 + fm * 16 + g * 4 + r;
            if (row < M) {
#pragma unroll
                for (int fn = 0; fn < 3; ++fn) {
                    int col = fn * 16 + l16;
                    float v = acc[fm][fn][r];
                    if (col < 20) {
                        int h = col / 5, c = col % 5;
                        xlb[((size_t)row * 4 + h) * 8 + c] = f2bf(v + bl[col]);
                    } else if (col < 40) {
                        int cc = col - 20, h = cc / 5, c = cc % 5;
                        xrb[((size_t)row * 4 + h) * 8 + c] = f2bf(v + br[cc]);
                    }
                }
            }
        }
    }
}

// ---------- gat_node layer 2 standalone ----------
__global__ void gat_node2(const int2* __restrict__ se2, const int* __restrict__ off2,
                          const unsigned short* __restrict__ xlb, const unsigned short* __restrict__ xrb,
                          const float* __restrict__ We, const float* __restrict__ att,
                          const float* __restrict__ b,
                          const float* __restrict__ bng, const float* __restrict__ bnb,
                          unsigned short* __restrict__ z, int N)
{
    int t = blockIdx.x * blockDim.x + threadIdx.x;
    if (t >= N * 4) return;
    gat_node_core<4, 5, 8, 2>(se2, off2, xlb, xrb, We, att, b, bng, bnb, (void*)z, t >> 2, t & 3);
}

// ---------- MLP head via MFMA ----------
__global__ __launch_bounds__(256) void mlp_mfma(
    const unsigned short* __restrict__ z, const float* __restrict__ addf,
    const unsigned short* __restrict__ Bt1p,
    const float* __restrict__ fc1b, const float* __restrict__ bnfg, const float* __restrict__ bnfb,
    const float* __restrict__ fc2W, const float* __restrict__ fc2b,
    float* __restrict__ out, int M)
{
    __shared__ __align__(16) char smem[64 * 169 * 4];
    unsigned short (*zs)[200] = reinterpret_cast<unsigned short(*)[200]>(smem);
    float (*ts)[169] = reinterpret_cast<float(*)[169]>(smem);
    const int tid = threadIdx.x;
    const int wid = tid >> 6, lane = tid & 63;
    const int m0 = blockIdx.x * 64;
    const int l16 = lane & 15, g = lane >> 4;
    const short8* Bv = reinterpret_cast<const short8*>(Bt1p);

#pragma unroll
    for (int p = 0; p < 13; ++p) {
        int idx = p * 256 + tid;
        if (idx < 3200) {
            int row = idx / 50, c4 = (idx % 50) * 4;
            int ar = m0 + row;
            ushort4 u; u.x = 0; u.y = 0; u.z = 0; u.w = 0;
            if (ar < M) {
                if (c4 < 148) {
                    u = *reinterpret_cast<const ushort4*>(&z[(size_t)ar * 168 + c4]);
                } else if (c4 < 168) {
                    float4 v = *reinterpret_cast<const float4*>(&addf[(size_t)ar * 20 + (c4 - 148)]);
                    u.x = f2bf(v.x); u.y = f2bf(v.y); u.z = f2bf(v.z); u.w = f2bf(v.w);
                }
            }
            *reinterpret_cast<ushort4*>(&zs[row][c4]) = u;
        }
    }
    __syncthreads();

    f32x4 acc[4][4] = {};
    if (wid < 3) {
#pragma unroll
        for (int t = 0; t < 6; ++t) {
            short8 afr[4], bfr[4];
#pragma unroll
            for (int fm = 0; fm < 4; ++fm)
                afr[fm] = *reinterpret_cast<const short8*>(&zs[fm * 16 + l16][t * 32 + g * 8]);
#pragma unroll
            for (int fn = 0; fn < 4; ++fn)
                bfr[fn] = Bv[((t * 3 + wid) * 4 + fn) * 64 + lane];
#pragma unroll
            for (int fm = 0; fm < 4; ++fm)
#pragma unroll
                for (int fn = 0; fn < 4; ++fn)
                    acc[fm][fn] = __builtin_amdgcn_mfma_f32_16x16x32_bf16(
                        afr[fm], bfr[fn], acc[fm][fn], 0, 0, 0);
        }
    }
    __syncthreads();
    if (wid < 3) {
        const int colbase = wid * 64 + l16;
#pragma unroll
        for (int fm = 0; fm < 4; ++fm) {
#pragma unroll
            for (int r = 0; r < 4; ++r) {
                int rr = fm * 16 + g * 4 + r;
#pragma unroll
                for (int fn = 0; fn < 4; ++fn) {
                    int col = colbase + fn * 16;
                    if (col < 168) {
                        float v = acc[fm][fn][r] + fc1b[col];
                        v = v * (bnfg[col] * BN_RSQ) + bnfb[col];
                        ts[rr][col] = fmaxf(v, 0.0f);
                    }
                }
            }
        }
    }
    __syncthreads();
    if (tid < 192) {
        int r = tid & 63, c = tid >> 6;
        float acc2 = fc2b[c];
#pragma unroll 4
        for (int k = 0; k < 168; ++k) acc2 += ts[r][k] * fc2W[k * 3 + c];
        int row = m0 + r;
        if (row < M) out[(size_t)row * 3 + c] = acc2;
    }
}

// ---------- launch ----------
extern "C" void kernel_launch(void* const* d_in, const int* in_sizes, int n_in,
                              void* d_out, int out_size, void* d_ws, size_t ws_size,
                              hipStream_t stream)
{
    const float* features = (const float*)d_in[0];
    const int*   e1       = (const int*)d_in[1];
    const int*   e2       = (const int*)d_in[2];
    const float* ef       = (const float*)d_in[3];
    const float* addf     = (const float*)d_in[4];
    const float* sage_Wl  = (const float*)d_in[5];
    const float* sage_bl  = (const float*)d_in[6];
    const float* sage_Wr  = (const float*)d_in[7];
    const float* g1_Wl = (const float*)d_in[8];
    const float* g1_bl = (const float*)d_in[9];
    const float* g1_Wr = (const float*)d_in[10];
    const float* g1_br = (const float*)d_in[11];
    const float* g1_We = (const float*)d_in[12];
    const float* g1_att = (const float*)d_in[13];
    const float* g1_b = (const float*)d_in[14];
    const float* g2_Wl = (const float*)d_in[15];
    const float* g2_bl = (const float*)d_in[16];
    const float* g2_Wr = (const float*)d_in[17];
    const float* g2_br = (const float*)d_in[18];
    const float* g2_We = (const float*)d_in[19];
    const float* g2_att = (const float*)d_in[20];
    const float* g2_b = (const float*)d_in[21];
    const float* fc1_W = (const float*)d_in[22];
    const float* fc1_b = (const float*)d_in[23];
    const float* fc2_W = (const float*)d_in[24];
    const float* fc2_b = (const float*)d_in[25];
    const float* bnx_g = (const float*)d_in[26];
    const float* bnx_b = (const float*)d_in[27];
    const float* bny_g = (const float*)d_in[28];
    const float* bny_b = (const float*)d_in[29];
    const float* bnf_g = (const float*)d_in[30];
    const float* bnf_b = (const float*)d_in[31];

    const int N = in_sizes[0] / 1024;
    const int E = in_sizes[3];
    const int Eext = E + N;
    const int* e1s = e1, *e1d = e1 + E;
    const int* e2s = e2, *e2d = e2 + E;
    const int nb = (N + SCAN_B - 1) / SCAN_B;

    char* wb = (char*)d_ws;
    size_t off = 0;
    auto takeB = [&](size_t bytes) { char* p = wb + off; off = (off + bytes + 255) & ~(size_t)255; return p; };
    unsigned short* P = (unsigned short*)takeB((size_t)N * 256 * 2);
    unsigned short* z = (unsigned short*)takeB((size_t)N * 168 * 2);
    float* ealoop = (float*)takeB((size_t)N * 4);
    unsigned short* xl1b = (unsigned short*)takeB((size_t)N * 64 * 2);
    unsigned short* xr1b = (unsigned short*)takeB((size_t)N * 64 * 2);
    float* y1 = (float*)takeB((size_t)N * 40 * 4);
    unsigned short* xl2b = (unsigned short*)takeB((size_t)N * 32 * 2);
    unsigned short* xr2b = (unsigned short*)takeB((size_t)N * 32 * 2);
    unsigned short* Btp  = (unsigned short*)takeB((size_t)256 * 1024 * 2);
    unsigned short* Bt1p = (unsigned short*)takeB((size_t)36864 * 2);
    unsigned short* Bg1  = (unsigned short*)takeB((size_t)2560 * 2);
    unsigned short* Bg2  = (unsigned short*)takeB((size_t)3072 * 2);
    char* zero_beg = wb + off;
    int* cnt1    = (int*)takeB((size_t)N * 4);
    int* cnt2    = (int*)takeB((size_t)N * 4);
    float* easum = (float*)takeB((size_t)N * 4);
    size_t zero_len = (size_t)((wb + off) - zero_beg);
    int* off1  = (int*)takeB((size_t)(N + 1) * 4);
    int* off2  = (int*)takeB((size_t)(N + 1) * 4);
    int* bsum1 = (int*)takeB(SCAN_B * 4);
    int* bsum2 = (int*)takeB(SCAN_B * 4);
    int* srcs1 = (int*)takeB((size_t)E * 4);
    int2* se2  = (int2*)takeB((size_t)Eext * 8);

    const int B = 256;
    const int n16 = (int)(zero_len / 16);
    zero_ws<<<(n16 + B - 1) / B, B, 0, stream>>>((uint4*)zero_beg, n16);

    const int prep_total = 262144 + 36864 + 2560 + 3072 + E;
    prep_all<<<(prep_total + B - 1) / B, B, 0, stream>>>(
        sage_Wl, sage_Wr, Btp, fc1_W, Bt1p,
        g1_Wl, g1_Wr, Bg1, g2_Wl, g2_Wr, Bg2,
        e1d, e2d, ef, cnt1, cnt2, easum, E);

    scan1<<<dim3(nb, 2), SCAN_B, 0, stream>>>(cnt1, cnt2, off1, off2, bsum1, bsum2, N);
    scan2<<<dim3(1, 2), SCAN_B, 0, stream>>>(bsum1, bsum2, nb);
    scan3<<<dim3(nb, 2), SCAN_B, 0, stream>>>(off1, off2, bsum1, bsum2, cnt1, cnt2,
                                              easum, ealoop, N);

    // stageA: gemm || CSR fill || gat_lin1
    const int mtiles = (N + 63) / 64;
    const int Gf = (E + Eext + B - 1) / B;
    const int Gl = (mtiles + 3) / 4;
    stageA<<<mtiles + Gf + Gl, 256, 0, stream>>>(
        features, Btp, P,
        e1s, e1d, e2s, e2d, ef, ealoop, off1, off2, cnt1, cnt2, srcs1, se2,
        addf, Bg1, g1_bl, g1_br, xl1b, xr1b,
        N, E, Eext, mtiles, Gf);

    // stageB: sage_gather || gat_node layer1
    const int Gg = (N * 16 + B - 1) / B;
    const int Gn = (N * 4 + B - 1) / B;
    stageB<<<Gg + Gn, 256, 0, stream>>>(
        srcs1, off1, P, sage_bl, bnx_g, bnx_b, z,
        se2, off2, xl1b, xr1b, g1_We, g1_att, g1_b, y1, N, Gg);

    gat_lin2_mfma<<<mtiles, 64, 0, stream>>>(y1, Bg2, g2_bl, g2_br, xl2b, xr2b, N);
    gat_node2<<<Gn, 256, 0, stream>>>(se2, off2, xl2b, xr2b, g2_We, g2_att, g2_b,
                                      bny_g, bny_b, z, N);

    mlp_mfma<<<mtiles, 256, 0, stream>>>(z, addf, Bt1p, fc1_b, bnf_g, bnf_b, fc2_W, fc2_b,
                                         (float*)d_out, N);
}

// Round 15
// 258.801 us; speedup vs baseline: 1.1703x; 1.0068x over previous
//
#include <hip/hip_runtime.h>
#include <hip/hip_bf16.h>
#include <cfloat>

__device__ __forceinline__ float lrelu(float x, float a) { return x > 0.0f ? x : a * x; }

__device__ __forceinline__ unsigned short f2bf(float f) {
    unsigned u = __float_as_uint(f);
    unsigned r = (u + 0x7FFFu + ((u >> 16) & 1u)) >> 16;
    return (unsigned short)r;
}
__device__ __forceinline__ float bf2f(unsigned short u) {
    return __uint_as_float((unsigned)u << 16);
}

typedef __attribute__((ext_vector_type(8))) short short8;
typedef __attribute__((ext_vector_type(4))) float f32x4;

#define BN_RSQ 0.99999500003749968750f
#define SCAN_B 256
// barrier that drains LDS ops only — keeps global loads (vmcnt) in flight
#define BAR_LGKM() asm volatile("s_waitcnt lgkmcnt(0)\n\ts_barrier" ::: "memory")

// ---------- fast zero ----------
__global__ void zero_ws(uint4* __restrict__ p, int n16)
{
    int t = blockIdx.x * blockDim.x + threadIdx.x;
    if (t < n16) p[t] = make_uint4(0u, 0u, 0u, 0u);
}

// ---------- fused prep ----------
__global__ void prep_all(const float* __restrict__ sWl, const float* __restrict__ sWr,
                         unsigned short* __restrict__ Btp,
                         const float* __restrict__ fc1W, unsigned short* __restrict__ Bt1p,
                         const float* __restrict__ g1Wl, const float* __restrict__ g1Wr,
                         unsigned short* __restrict__ Bg1,
                         const float* __restrict__ g2Wl, const float* __restrict__ g2Wr,
                         unsigned short* __restrict__ Bg2,
                         const int* __restrict__ e1d, const int* __restrict__ e2d,
                         const float* __restrict__ ef,
                         int* __restrict__ cnt1, int* __restrict__ cnt2,
                         float* __restrict__ easum, int E)
{
    int idx = blockIdx.x * blockDim.x + threadIdx.x;
    if (idx < 262144) {
        int j = idx & 7, lane = (idx >> 3) & 63, fn = (idx >> 9) & 3, wid = (idx >> 11) & 3, t = idx >> 13;
        int c = wid * 64 + fn * 16 + (lane & 15);
        int k = t * 32 + (lane >> 4) * 8 + j;
        float v = (c < 128) ? sWl[(size_t)k * 128 + c] : sWr[(size_t)k * 128 + (c - 128)];
        Btp[idx] = f2bf(v);
        return;
    }
    idx -= 262144;
    if (idx < 36864) {
        int j = idx & 7, lane = (idx >> 3) & 63, fn = (idx >> 9) & 3, q = idx >> 11;
        int wid = q % 3, t = q / 3;
        int c = wid * 64 + fn * 16 + (lane & 15);
        int k = t * 32 + (lane >> 4) * 8 + j;
        float v = (c < 168 && k < 168) ? fc1W[(size_t)k * 168 + c] : 0.0f;
        Bt1p[idx] = f2bf(v);
        return;
    }
    idx -= 36864;
    if (idx < 2560) {
        int j = idx & 7, lane = (idx >> 3) & 63, fn = idx >> 9;
        int c = fn * 16 + (lane & 15);
        int k = (lane >> 4) * 8 + j;
        float v = 0.0f;
        if (k < 20) v = (c < 40) ? g1Wl[(size_t)k * 40 + c] : g1Wr[(size_t)k * 40 + (c - 40)];
        Bg1[idx] = f2bf(v);
        return;
    }
    idx -= 2560;
    if (idx < 3072) {
        int j = idx & 7, lane = (idx >> 3) & 63, q = idx >> 9;
        int fn = q % 3, t = q / 3;
        int c = fn * 16 + (lane & 15);
        int k = t * 32 + (lane >> 4) * 8 + j;
        float v = 0.0f;
        if (k < 40 && c < 40) v = (c < 20) ? g2Wl[(size_t)k * 20 + c] : g2Wr[(size_t)k * 20 + (c - 20)];
        Bg2[idx] = f2bf(v);
        return;
    }
    idx -= 3072;
    if (idx < E) {
        atomicAdd(&cnt1[e1d[idx]], 1);
        int d2 = e2d[idx];
        atomicAdd(&cnt2[d2], 1);
        atomicAdd(&easum[d2], ef[idx]);
    }
}

// ---------- exclusive scans ----------
__global__ void scan1(const int* __restrict__ cnt1, const int* __restrict__ cnt2,
                      int* __restrict__ off1, int* __restrict__ off2,
                      int* __restrict__ bsum1, int* __restrict__ bsum2, int M)
{
    __shared__ int sh[SCAN_B];
    int y = blockIdx.y;
    const int* cnt = y ? cnt2 : cnt1;
    int* excl = y ? off2 : off1;
    int* bsum = y ? bsum2 : bsum1;
    int i = blockIdx.x * SCAN_B + threadIdx.x;
    int v = (i < M) ? cnt[i] + y : 0;
    sh[threadIdx.x] = v;
    __syncthreads();
    for (int o = 1; o < SCAN_B; o <<= 1) {
        int t = (threadIdx.x >= o) ? sh[threadIdx.x - o] : 0;
        __syncthreads();
        sh[threadIdx.x] += t;
        __syncthreads();
    }
    if (i < M) excl[i] = sh[threadIdx.x] - v;
    if (threadIdx.x == SCAN_B - 1) bsum[blockIdx.x] = sh[threadIdx.x];
}

__global__ void scan2(int* __restrict__ bsum1, int* __restrict__ bsum2, int nb)
{
    __shared__ int sh[SCAN_B];
    int* bsum = blockIdx.y ? bsum2 : bsum1;
    int v = ((int)threadIdx.x < nb) ? bsum[threadIdx.x] : 0;
    sh[threadIdx.x] = v;
    __syncthreads();
    for (int o = 1; o < SCAN_B; o <<= 1) {
        int t = (threadIdx.x >= o) ? sh[threadIdx.x - o] : 0;
        __syncthreads();
        sh[threadIdx.x] += t;
        __syncthreads();
    }
    if ((int)threadIdx.x < nb) bsum[threadIdx.x] = sh[threadIdx.x] - v;
}

__global__ void scan3(int* __restrict__ off1, int* __restrict__ off2,
                      const int* __restrict__ bsum1, const int* __restrict__ bsum2,
                      const int* __restrict__ cnt1, const int* __restrict__ cnt2,
                      const float* __restrict__ easum, float* __restrict__ ealoop, int M)
{
    int y = blockIdx.y;
    int* off = y ? off2 : off1;
    const int* bsum = y ? bsum2 : bsum1;
    const int* cnt = y ? cnt2 : cnt1;
    int i = blockIdx.x * SCAN_B + threadIdx.x;
    if (i < M) {
        int v = off[i] + bsum[blockIdx.x];
        off[i] = v;
        if (i == M - 1) off[M] = v + cnt[i] + y;
        if (y) ealoop[i] = easum[i] / fmaxf((float)cnt2[i], 1.0f);
    }
}

// ---------- stageA: gemm (blocks [0,Gg)) || CSR fill (next Gf) || GAT1 lin (rest) ----------
__global__ __launch_bounds__(256) void stageA(
    const float* __restrict__ A, const unsigned short* __restrict__ Btp,
    unsigned short* __restrict__ P,
    const int* __restrict__ e1s, const int* __restrict__ e1d,
    const int* __restrict__ e2s, const int* __restrict__ e2d,
    const float* __restrict__ ef, const float* __restrict__ ealoop,
    const int* __restrict__ off1, const int* __restrict__ off2,
    int* __restrict__ cnt1, int* __restrict__ cnt2,
    int* __restrict__ srcs1, int2* __restrict__ se2,
    const float* __restrict__ addf, const unsigned short* __restrict__ Bg1,
    const float* __restrict__ g1bl, const float* __restrict__ g1br,
    unsigned short* __restrict__ xl1b, unsigned short* __restrict__ xr1b,
    int M, int E, int Eext, int Gg, int Gf)
{
    __shared__ __align__(16) char smem[20480];
    const int bid = blockIdx.x;
    const int tid = threadIdx.x;

    if (bid < Gg) {
        // ===== GEMM path: B-first loads + lgkmcnt-only barrier (A prefetch survives) =====
        typedef unsigned short As2_t[64][72];
        As2_t* As2 = reinterpret_cast<As2_t*>(smem);
        const int wid = tid >> 6, lane = tid & 63;
        const int m0 = bid * 64;
        const int l16 = lane & 15, g = lane >> 4;
        const int colbase = wid * 64 + l16;
        const short8* Bv = reinterpret_cast<const short8*>(Btp);
        const int srow = tid >> 4, scol = (tid & 15) * 4;

        f32x4 acc[4][4] = {};
        float4 rcur[4], rnext[4];

#pragma unroll
        for (int p = 0; p < 4; ++p) {
            int ar = m0 + p * 16 + srow;
            rcur[p] = make_float4(0.f, 0.f, 0.f, 0.f);
            if (ar < M) rcur[p] = *reinterpret_cast<const float4*>(&A[(size_t)ar * 1024 + scol]);
        }
#pragma unroll
        for (int p = 0; p < 4; ++p) {
            ushort4 u;
            u.x = f2bf(rcur[p].x); u.y = f2bf(rcur[p].y); u.z = f2bf(rcur[p].z); u.w = f2bf(rcur[p].w);
            *reinterpret_cast<ushort4*>(&As2[0][p * 16 + srow][scol]) = u;
        }
#pragma unroll
        for (int p = 0; p < 4; ++p) {
            int ar = m0 + p * 16 + srow;
            rcur[p] = make_float4(0.f, 0.f, 0.f, 0.f);
            if (ar < M) rcur[p] = *reinterpret_cast<const float4*>(&A[(size_t)ar * 1024 + 64 + scol]);
        }
        BAR_LGKM();

        for (int c = 0; c < 16; ++c) {
            const int buf = c & 1;
            // 1) B fragments for this chunk (L2-resident), issued FIRST so the
            //    MFMA's implicit vmcnt wait retires them without draining the A prefetch
            short8 bfr[2][4];
#pragma unroll
            for (int t = 0; t < 2; ++t)
#pragma unroll
                for (int fn = 0; fn < 4; ++fn)
                    bfr[t][fn] = Bv[(((c * 2 + t) * 4 + wid) * 4 + fn) * 64 + lane];
            // 2) A prefetch for chunk c+2
            if (c < 14) {
                const int k0 = (c + 2) * 64;
#pragma unroll
                for (int p = 0; p < 4; ++p) {
                    int ar = m0 + p * 16 + srow;
                    rnext[p] = make_float4(0.f, 0.f, 0.f, 0.f);
                    if (ar < M) rnext[p] = *reinterpret_cast<const float4*>(&A[(size_t)ar * 1024 + k0 + scol]);
                }
            }
            // 3) compute
#pragma unroll
            for (int t = 0; t < 2; ++t) {
                short8 afr[4];
#pragma unroll
                for (int fm = 0; fm < 4; ++fm)
                    afr[fm] = *reinterpret_cast<const short8*>(&As2[buf][fm * 16 + l16][t * 32 + g * 8]);
#pragma unroll
                for (int fm = 0; fm < 4; ++fm)
#pragma unroll
                    for (int fn = 0; fn < 4; ++fn)
                        acc[fm][fn] = __builtin_amdgcn_mfma_f32_16x16x32_bf16(
                            afr[fm], bfr[t][fn], acc[fm][fn], 0, 0, 0);
            }
            // 4) stage chunk c+1 (rcur = loads issued one chunk ago)
            if (c < 15) {
#pragma unroll
                for (int p = 0; p < 4; ++p) {
                    ushort4 u;
                    u.x = f2bf(rcur[p].x); u.y = f2bf(rcur[p].y);
                    u.z = f2bf(rcur[p].z); u.w = f2bf(rcur[p].w);
                    *reinterpret_cast<ushort4*>(&As2[buf ^ 1][p * 16 + srow][scol]) = u;
                }
            }
            // 5) LDS-only barrier
            BAR_LGKM();
#pragma unroll
            for (int p = 0; p < 4; ++p) rcur[p] = rnext[p];
        }

#pragma unroll
        for (int fm = 0; fm < 4; ++fm) {
#pragma unroll
            for (int r = 0; r < 4; ++r) {
                int row = m0 + fm * 16 + g * 4 + r;
                if (row < M) {
#pragma unroll
                    for (int fn = 0; fn < 4; ++fn)
                        P[(size_t)row * 256 + colbase + fn * 16] = f2bf(acc[fm][fn][r]);
                }
            }
        }
    } else if (bid < Gg + Gf) {
        // ===== CSR fill path =====
        int t = (bid - Gg) * 256 + tid;
        if (t < E) {
            int d = e1d[t];
            int pos = atomicSub(&cnt1[d], 1) - 1;
            srcs1[off1[d] + pos] = e1s[t];
        }
        int t2 = t - E;
        if (t2 >= 0 && t2 < Eext) {
            if (t2 < E) {
                int d = e2d[t2];
                int pos = atomicSub(&cnt2[d], 1) - 1;
                se2[off2[d] + pos] = make_int2(e2s[t2], __float_as_int(ef[t2]));
            } else {
                int nn = t2 - E;
                se2[off2[nn + 1] - 1] = make_int2(nn, __float_as_int(ealoop[nn]));
            }
        }
    } else {
        // ===== GAT1 linear path: 4 waves, each one 64-row tile; bf16 out, PAD=16 =====
        const int wid = tid >> 6, lane = tid & 63;
        const int tile = (bid - Gg - Gf) * 4 + wid;
        const int m0 = tile * 64;
        if (m0 >= M) return;
        unsigned short (*xs)[40] = reinterpret_cast<unsigned short(*)[40]>(smem + wid * 5120);
        const int l16 = lane & 15, g = lane >> 4;
        const short8* Bv = reinterpret_cast<const short8*>(Bg1);

#pragma unroll
        for (int i = 0; i < 5; ++i) {
            int q = i * 64 + lane;
            int f = q * 4;
            int row = f / 20, col = f % 20;
            int ar = m0 + row;
            float4 v = make_float4(0.f, 0.f, 0.f, 0.f);
            if (ar < M) v = *reinterpret_cast<const float4*>(&addf[(size_t)ar * 20 + col]);
            ushort4 u;
            u.x = f2bf(v.x); u.y = f2bf(v.y); u.z = f2bf(v.z); u.w = f2bf(v.w);
            *reinterpret_cast<ushort4*>(&xs[row][col]) = u;
        }
        ushort4 zz; zz.x = 0; zz.y = 0; zz.z = 0; zz.w = 0;
#pragma unroll
        for (int c = 20; c < 32; c += 4)
            *reinterpret_cast<ushort4*>(&xs[lane][c]) = zz;

        f32x4 acc[4][5] = {};
        short8 afr[4], bfr[5];
#pragma unroll
        for (int fm = 0; fm < 4; ++fm)
            afr[fm] = *reinterpret_cast<const short8*>(&xs[fm * 16 + l16][g * 8]);
#pragma unroll
        for (int fn = 0; fn < 5; ++fn)
            bfr[fn] = Bv[fn * 64 + lane];
#pragma unroll
        for (int fm = 0; fm < 4; ++fm)
#pragma unroll
            for (int fn = 0; fn < 5; ++fn)
                acc[fm][fn] = __builtin_amdgcn_mfma_f32_16x16x32_bf16(
                    afr[fm], bfr[fn], acc[fm][fn], 0, 0, 0);

#pragma unroll
        for (int fm = 0; fm < 4; ++fm) {
#pragma unroll
            for (int r = 0; r < 4; ++r) {
                int row = m0 + fm * 16 + g * 4 + r;
                if (row < M) {
#pragma unroll
                    for (int fn = 0; fn < 5; ++fn) {
                        int col = fn * 16 + l16;
                        float v = acc[fm][fn][r];
                        if (col < 40) {
                            int h = col / 10, c = col % 10;
                            xl1b[((size_t)row * 4 + h) * 16 + c] = f2bf(v + g1bl[col]);
                        } else if (col < 80) {
                            int cc = col - 40, h = cc / 10, c = cc % 10;
                            xr1b[((size_t)row * 4 + h) * 16 + c] = f2bf(v + g1br[cc]);
                        }
                    }
                }
            }
        }
    }
}

// ---------- fused GATv2 node core (device helper) ----------
template <int H, int C, int BPAD>
__device__ __forceinline__ void gat_node_compute(
    const int2* __restrict__ se2, const int* __restrict__ off2,
    const unsigned short* __restrict__ xlb, const unsigned short* __restrict__ xrb,
    const float* __restrict__ We, const float* __restrict__ att,
    int n, int h, float* __restrict__ outc)
{
    float xrc[C], atth[C], weh[C];
    {
        short8 sv[BPAD / 8];
#pragma unroll
        for (int q = 0; q < BPAD / 8; ++q)
            sv[q] = *reinterpret_cast<const short8*>(&xrb[((size_t)n * H + h) * BPAD + q * 8]);
#pragma unroll
        for (int c = 0; c < C; ++c) xrc[c] = bf2f((unsigned short)sv[c / 8][c % 8]);
    }
#pragma unroll
    for (int c = 0; c < C; ++c) {
        atth[c] = att[h * C + c];
        weh[c]  = We[h * C + c];
    }

    const int beg = off2[n], end = off2[n + 1];
    float mx = -FLT_MAX, den = 0.0f;
    float accv[C] = {};
    for (int j = beg; j < end; ++j) {
        int2 se = se2[j];
        int s = se.x;
        float ea = __int_as_float(se.y);
        short8 sv[BPAD / 8];
#pragma unroll
        for (int q = 0; q < BPAD / 8; ++q)
            sv[q] = *reinterpret_cast<const short8*>(&xlb[((size_t)s * H + h) * BPAD + q * 8]);
        float xv[C];
        float lg = 0.0f;
#pragma unroll
        for (int c = 0; c < C; ++c) {
            xv[c] = bf2f((unsigned short)sv[c / 8][c % 8]);
            float m = xv[c] + xrc[c] + ea * weh[c];
            lg += lrelu(m, 0.2f) * atth[c];
        }
        if (lg > mx) {
            float sc = __expf(mx - lg);
            den *= sc;
#pragma unroll
            for (int c = 0; c < C; ++c) accv[c] *= sc;
            mx = lg;
        }
        float ex = __expf(lg - mx);
        den += ex;
#pragma unroll
        for (int c = 0; c < C; ++c) accv[c] += ex * xv[c];
    }
    float inv = 1.0f / (den + 1e-16f);
#pragma unroll
    for (int c = 0; c < C; ++c) outc[c] = accv[c] * inv;
}

// ---------- stageB: sage_gather (blocks [0,Gg)) || gat_node layer1 (rest) ----------
__global__ void stageB(const int* __restrict__ srcs1, const int* __restrict__ off1,
                       const unsigned short* __restrict__ P, const float* __restrict__ bl,
                       const float* __restrict__ bng, const float* __restrict__ bnb,
                       unsigned short* __restrict__ z128,
                       const int2* __restrict__ se2, const int* __restrict__ off2,
                       const unsigned short* __restrict__ xl1b, const unsigned short* __restrict__ xr1b,
                       const float* __restrict__ g1We, const float* __restrict__ g1att,
                       const float* __restrict__ g1b, float* __restrict__ y1,
                       int N, int Gg)
{
    const int bid = blockIdx.x;
    if (bid < Gg) {
        int t = bid * 256 + threadIdx.x;
        if (t >= N * 16) return;
        int n = t >> 4, g = t & 15;
        int beg = off1[n], end = off1[n + 1];
        float a[8] = {};
        for (int j = beg; j < end; ++j) {
            int s = srcs1[j];
            short8 v = *reinterpret_cast<const short8*>(&P[(size_t)s * 256 + g * 8]);
#pragma unroll
            for (int k = 0; k < 8; ++k) a[k] += bf2f((unsigned short)v[k]);
        }
        float inv = 1.0f / fmaxf((float)(end - beg), 1.0f);
        short8 pr = *reinterpret_cast<const short8*>(&P[(size_t)n * 256 + 128 + g * 8]);
        short8 zo;
#pragma unroll
        for (int k = 0; k < 8; ++k) {
            int cc = g * 8 + k;
            float x = a[k] * inv + bl[cc] + bf2f((unsigned short)pr[k]);
            x = x * (bng[cc] * BN_RSQ) + bnb[cc];
            zo[k] = (short)f2bf(lrelu(x, 0.01f));
        }
        *reinterpret_cast<short8*>(&z128[(size_t)n * 128 + g * 8]) = zo;
    } else {
        int t = (bid - Gg) * 256 + threadIdx.x;
        if (t >= N * 4) return;
        int n = t >> 2, h = t & 3;
        float oc[10];
        gat_node_compute<4, 10, 16>(se2, off2, xl1b, xr1b, g1We, g1att, n, h, oc);
#pragma unroll
        for (int c = 0; c < 10; ++c) {
            int jch = h * 10 + c;
            y1[(size_t)n * 40 + jch] = lrelu(oc[c] + g1b[jch], 0.01f);
        }
    }
}

// ---------- GAT2 linear via MFMA: single-wave, bf16 out PAD=8 ----------
__global__ __launch_bounds__(64) void gat_lin2_mfma(
    const float* __restrict__ X, const unsigned short* __restrict__ Bp,
    const float* __restrict__ bl, const float* __restrict__ br,
    unsigned short* __restrict__ xlb, unsigned short* __restrict__ xrb, int M)
{
    __shared__ unsigned short xs[64][72];
    const int lane = threadIdx.x;
    const int m0 = blockIdx.x * 64;
    const int l16 = lane & 15, g = lane >> 4;
    const short8* Bv = reinterpret_cast<const short8*>(Bp);

#pragma unroll
    for (int i = 0; i < 10; ++i) {
        int q = i * 64 + lane;
        int f = q * 4;
        int row = f / 40, col = f % 40;
        int ar = m0 + row;
        float4 v = make_float4(0.f, 0.f, 0.f, 0.f);
        if (ar < M) v = *reinterpret_cast<const float4*>(&X[(size_t)ar * 40 + col]);
        ushort4 u;
        u.x = f2bf(v.x); u.y = f2bf(v.y); u.z = f2bf(v.z); u.w = f2bf(v.w);
        *reinterpret_cast<ushort4*>(&xs[row][col]) = u;
    }
    ushort4 zz; zz.x = 0; zz.y = 0; zz.z = 0; zz.w = 0;
#pragma unroll
    for (int c = 40; c < 64; c += 4)
        *reinterpret_cast<ushort4*>(&xs[lane][c]) = zz;

    f32x4 acc[4][3] = {};
#pragma unroll
    for (int t = 0; t < 2; ++t) {
        short8 afr[4], bfr[3];
#pragma unroll
        for (int fm = 0; fm < 4; ++fm)
            afr[fm] = *reinterpret_cast<const short8*>(&xs[fm * 16 + l16][t * 32 + g * 8]);
#pragma unroll
        for (int fn = 0; fn < 3; ++fn)
            bfr[fn] = Bv[(t * 3 + fn) * 64 + lane];
#pragma unroll
        for (int fm = 0; fm < 4; ++fm)
#pragma unroll
            for (int fn = 0; fn < 3; ++fn)
                acc[fm][fn] = __builtin_amdgcn_mfma_f32_16x16x32_bf16(
                    afr[fm], bfr[fn], acc[fm][fn], 0, 0, 0);
    }

#pragma unroll
    for (int fm = 0; fm < 4; ++fm) {
#pragma unroll
        for (int r = 0; r < 4; ++r) {
            int row = m0 + fm * 16 + g * 4 + r;
            if (row < M) {
#pragma unroll
                for (int fn = 0; fn < 3; ++fn) {
                    int col = fn * 16 + l16;
                    float v = acc[fm][fn][r];
                    if (col < 20) {
                        int h = col / 5, c = col % 5;
                        xlb[((size_t)row * 4 + h) * 8 + c] = f2bf(v + bl[col]);
                    } else if (col < 40) {
                        int cc = col - 20, h = cc / 5, c = cc % 5;
                        xrb[((size_t)row * 4 + h) * 8 + c] = f2bf(v + br[cc]);
                    }
                }
            }
        }
    }
}

// ---------- MLP head via MFMA, with GAT2-node fused in (1 node-head per thread) ----------
__global__ __launch_bounds__(256) void mlp_mfma(
    const unsigned short* __restrict__ z128, const float* __restrict__ addf,
    const int2* __restrict__ se2, const int* __restrict__ off2,
    const unsigned short* __restrict__ xl2b, const unsigned short* __restrict__ xr2b,
    const float* __restrict__ g2We, const float* __restrict__ g2att,
    const float* __restrict__ g2b,
    const float* __restrict__ bnyg, const float* __restrict__ bnyb,
    const unsigned short* __restrict__ Bt1p,
    const float* __restrict__ fc1b, const float* __restrict__ bnfg, const float* __restrict__ bnfb,
    const float* __restrict__ fc2W, const float* __restrict__ fc2b,
    float* __restrict__ out, int M)
{
    __shared__ __align__(16) char smem[64 * 169 * 4];
    unsigned short (*zs)[200] = reinterpret_cast<unsigned short(*)[200]>(smem);
    float (*ts)[169] = reinterpret_cast<float(*)[169]>(smem);
    const int tid = threadIdx.x;
    const int wid = tid >> 6, lane = tid & 63;
    const int m0 = blockIdx.x * 64;
    const int l16 = lane & 15, g = lane >> 4;
    const short8* Bv = reinterpret_cast<const short8*>(Bt1p);

    // GAT2 node for this tile's rows: thread t -> (row = t>>2, head = t&3)
    {
        int row = tid >> 2, h = tid & 3;
        int n = m0 + row;
        if (n < M) {
            float oc[5];
            gat_node_compute<4, 5, 8>(se2, off2, xl2b, xr2b, g2We, g2att, n, h, oc);
#pragma unroll
            for (int c = 0; c < 5; ++c) {
                int jch = h * 5 + c;
                float v = oc[c] + g2b[jch];
                v = v * (bnyg[jch] * BN_RSQ) + bnyb[jch];
                zs[row][128 + jch] = f2bf(lrelu(v, 0.01f));
            }
        } else {
#pragma unroll
            for (int c = 0; c < 5; ++c) zs[row][128 + h * 5 + c] = 0;
        }
    }

    // stage z128 (cols 0..127), addf (148..167), zeros (168..199)
#pragma unroll
    for (int p = 0; p < 13; ++p) {
        int idx = p * 256 + tid;
        if (idx < 3200) {
            int row = idx / 50, c4 = (idx % 50) * 4;
            if (c4 >= 128 && c4 < 148) continue;   // node2 wrote these
            int ar = m0 + row;
            ushort4 u; u.x = 0; u.y = 0; u.z = 0; u.w = 0;
            if (ar < M) {
                if (c4 < 128) {
                    u = *reinterpret_cast<const ushort4*>(&z128[(size_t)ar * 128 + c4]);
                } else if (c4 >= 148 && c4 < 168) {
                    float4 v = *reinterpret_cast<const float4*>(&addf[(size_t)ar * 20 + (c4 - 148)]);
                    u.x = f2bf(v.x); u.y = f2bf(v.y); u.z = f2bf(v.z); u.w = f2bf(v.w);
                }
            }
            *reinterpret_cast<ushort4*>(&zs[row][c4]) = u;
        }
    }
    __syncthreads();

    f32x4 acc[4][4] = {};
    if (wid < 3) {
#pragma unroll
        for (int t = 0; t < 6; ++t) {
            short8 afr[4], bfr[4];
#pragma unroll
            for (int fm = 0; fm < 4; ++fm)
                afr[fm] = *reinterpret_cast<const short8*>(&zs[fm * 16 + l16][t * 32 + g * 8]);
#pragma unroll
            for (int fn = 0; fn < 4; ++fn)
                bfr[fn] = Bv[((t * 3 + wid) * 4 + fn) * 64 + lane];
#pragma unroll
            for (int fm = 0; fm < 4; ++fm)
#pragma unroll
                for (int fn = 0; fn < 4; ++fn)
                    acc[fm][fn] = __builtin_amdgcn_mfma_f32_16x16x32_bf16(
                        afr[fm], bfr[fn], acc[fm][fn], 0, 0, 0);
        }
    }
    __syncthreads();
    if (wid < 3) {
        const int colbase = wid * 64 + l16;
#pragma unroll
        for (int fm = 0; fm < 4; ++fm) {
#pragma unroll
            for (int r = 0; r < 4; ++r) {
                int rr = fm * 16 + g * 4 + r;
#pragma unroll
                for (int fn = 0; fn < 4; ++fn) {
                    int col = colbase + fn * 16;
                    if (col < 168) {
                        float v = acc[fm][fn][r] + fc1b[col];
                        v = v * (bnfg[col] * BN_RSQ) + bnfb[col];
                        ts[rr][col] = fmaxf(v, 0.0f);
                    }
                }
            }
        }
    }
    __syncthreads();
    if (tid < 192) {
        int r = tid & 63, c = tid >> 6;
        float acc2 = fc2b[c];
#pragma unroll 4
        for (int k = 0; k < 168; ++k) acc2 += ts[r][k] * fc2W[k * 3 + c];
        int row = m0 + r;
        if (row < M) out[(size_t)row * 3 + c] = acc2;
    }
}

// ---------- launch ----------
extern "C" void kernel_launch(void* const* d_in, const int* in_sizes, int n_in,
                              void* d_out, int out_size, void* d_ws, size_t ws_size,
                              hipStream_t stream)
{
    const float* features = (const float*)d_in[0];
    const int*   e1       = (const int*)d_in[1];
    const int*   e2       = (const int*)d_in[2];
    const float* ef       = (const float*)d_in[3];
    const float* addf     = (const float*)d_in[4];
    const float* sage_Wl  = (const float*)d_in[5];
    const float* sage_bl  = (const float*)d_in[6];
    const float* sage_Wr  = (const float*)d_in[7];
    const float* g1_Wl = (const float*)d_in[8];
    const float* g1_bl = (const float*)d_in[9];
    const float* g1_Wr = (const float*)d_in[10];
    const float* g1_br = (const float*)d_in[11];
    const float* g1_We = (const float*)d_in[12];
    const float* g1_att = (const float*)d_in[13];
    const float* g1_b = (const float*)d_in[14];
    const float* g2_Wl = (const float*)d_in[15];
    const float* g2_bl = (const float*)d_in[16];
    const float* g2_Wr = (const float*)d_in[17];
    const float* g2_br = (const float*)d_in[18];
    const float* g2_We = (const float*)d_in[19];
    const float* g2_att = (const float*)d_in[20];
    const float* g2_b = (const float*)d_in[21];
    const float* fc1_W = (const float*)d_in[22];
    const float* fc1_b = (const float*)d_in[23];
    const float* fc2_W = (const float*)d_in[24];
    const float* fc2_b = (const float*)d_in[25];
    const float* bnx_g = (const float*)d_in[26];
    const float* bnx_b = (const float*)d_in[27];
    const float* bny_g = (const float*)d_in[28];
    const float* bny_b = (const float*)d_in[29];
    const float* bnf_g = (const float*)d_in[30];
    const float* bnf_b = (const float*)d_in[31];

    const int N = in_sizes[0] / 1024;
    const int E = in_sizes[3];
    const int Eext = E + N;
    const int* e1s = e1, *e1d = e1 + E;
    const int* e2s = e2, *e2d = e2 + E;
    const int nb = (N + SCAN_B - 1) / SCAN_B;

    char* wb = (char*)d_ws;
    size_t off = 0;
    auto takeB = [&](size_t bytes) { char* p = wb + off; off = (off + bytes + 255) & ~(size_t)255; return p; };
    unsigned short* P = (unsigned short*)takeB((size_t)N * 256 * 2);
    unsigned short* z128 = (unsigned short*)takeB((size_t)N * 128 * 2);
    float* ealoop = (float*)takeB((size_t)N * 4);
    unsigned short* xl1b = (unsigned short*)takeB((size_t)N * 64 * 2);
    unsigned short* xr1b = (unsigned short*)takeB((size_t)N * 64 * 2);
    float* y1 = (float*)takeB((size_t)N * 40 * 4);
    unsigned short* xl2b = (unsigned short*)takeB((size_t)N * 32 * 2);
    unsigned short* xr2b = (unsigned short*)takeB((size_t)N * 32 * 2);
    unsigned short* Btp  = (unsigned short*)takeB((size_t)256 * 1024 * 2);
    unsigned short* Bt1p = (unsigned short*)takeB((size_t)36864 * 2);
    unsigned short* Bg1  = (unsigned short*)takeB((size_t)2560 * 2);
    unsigned short* Bg2  = (unsigned short*)takeB((size_t)3072 * 2);
    char* zero_beg = wb + off;
    int* cnt1    = (int*)takeB((size_t)N * 4);
    int* cnt2    = (int*)takeB((size_t)N * 4);
    float* easum = (float*)takeB((size_t)N * 4);
    size_t zero_len = (size_t)((wb + off) - zero_beg);
    int* off1  = (int*)takeB((size_t)(N + 1) * 4);
    int* off2  = (int*)takeB((size_t)(N + 1) * 4);
    int* bsum1 = (int*)takeB(SCAN_B * 4);
    int* bsum2 = (int*)takeB(SCAN_B * 4);
    int* srcs1 = (int*)takeB((size_t)E * 4);
    int2* se2  = (int2*)takeB((size_t)Eext * 8);

    const int B = 256;
    const int n16 = (int)(zero_len / 16);
    zero_ws<<<(n16 + B - 1) / B, B, 0, stream>>>((uint4*)zero_beg, n16);

    const int prep_total = 262144 + 36864 + 2560 + 3072 + E;
    prep_all<<<(prep_total + B - 1) / B, B, 0, stream>>>(
        sage_Wl, sage_Wr, Btp, fc1_W, Bt1p,
        g1_Wl, g1_Wr, Bg1, g2_Wl, g2_Wr, Bg2,
        e1d, e2d, ef, cnt1, cnt2, easum, E);

    scan1<<<dim3(nb, 2), SCAN_B, 0, stream>>>(cnt1, cnt2, off1, off2, bsum1, bsum2, N);
    scan2<<<dim3(1, 2), SCAN_B, 0, stream>>>(bsum1, bsum2, nb);
    scan3<<<dim3(nb, 2), SCAN_B, 0, stream>>>(off1, off2, bsum1, bsum2, cnt1, cnt2,
                                              easum, ealoop, N);

    // stageA: gemm || CSR fill || gat_lin1
    const int mtiles = (N + 63) / 64;
    const int Gf = (E + Eext + B - 1) / B;
    const int Gl = (mtiles + 3) / 4;
    stageA<<<mtiles + Gf + Gl, 256, 0, stream>>>(
        features, Btp, P,
        e1s, e1d, e2s, e2d, ef, ealoop, off1, off2, cnt1, cnt2, srcs1, se2,
        addf, Bg1, g1_bl, g1_br, xl1b, xr1b,
        N, E, Eext, mtiles, Gf);

    // stageB: sage_gather || gat_node layer1
    const int Gg = (N * 16 + B - 1) / B;
    const int Gn = (N * 4 + B - 1) / B;
    stageB<<<Gg + Gn, 256, 0, stream>>>(
        srcs1, off1, P, sage_bl, bnx_g, bnx_b, z128,
        se2, off2, xl1b, xr1b, g1_We, g1_att, g1_b, y1, N, Gg);

    gat_lin2_mfma<<<mtiles, 64, 0, stream>>>(y1, Bg2, g2_bl, g2_br, xl2b, xr2b, N);

    // mlp with GAT2-node fused
    mlp_mfma<<<mtiles, 256, 0, stream>>>(
        z128, addf, se2, off2, xl2b, xr2b, g2_We, g2_att, g2_b, bny_g, bny_b,
        Bt1p, fc1_b, bnf_g, bnf_b, fc2_W, fc2_b, (float*)d_out, N);
}

// Round 17
// 246.385 us; speedup vs baseline: 1.2293x; 1.0504x over previous
//
#include <hip/hip_runtime.h>
#include <hip/hip_bf16.h>
#include <cfloat>

__device__ __forceinline__ float lrelu(float x, float a) { return x > 0.0f ? x : a * x; }

__device__ __forceinline__ unsigned short f2bf(float f) {
    unsigned u = __float_as_uint(f);
    unsigned r = (u + 0x7FFFu + ((u >> 16) & 1u)) >> 16;
    return (unsigned short)r;
}
__device__ __forceinline__ float bf2f(unsigned short u) {
    return __uint_as_float((unsigned)u << 16);
}

typedef __attribute__((ext_vector_type(8))) short short8;
typedef __attribute__((ext_vector_type(4))) float f32x4;

#define BN_RSQ 0.99999500003749968750f
#define SCAN_B 256
// barrier that drains LDS ops only — compiler inserts precise vmcnt at register-use sites
#define BAR_LGKM() asm volatile("s_waitcnt lgkmcnt(0)\n\ts_barrier" ::: "memory")

// ---------- fast zero ----------
__global__ void zero_ws(uint4* __restrict__ p, int n16)
{
    int t = blockIdx.x * blockDim.x + threadIdx.x;
    if (t < n16) p[t] = make_uint4(0u, 0u, 0u, 0u);
}

// ---------- fused prep ----------
__global__ void prep_all(const float* __restrict__ sWl, const float* __restrict__ sWr,
                         unsigned short* __restrict__ Btp,
                         const float* __restrict__ fc1W, unsigned short* __restrict__ Bt1p,
                         const float* __restrict__ g1Wl, const float* __restrict__ g1Wr,
                         unsigned short* __restrict__ Bg1,
                         const float* __restrict__ g2Wl, const float* __restrict__ g2Wr,
                         unsigned short* __restrict__ Bg2,
                         const int* __restrict__ e1d, const int* __restrict__ e2d,
                         const float* __restrict__ ef,
                         int* __restrict__ cnt1, int* __restrict__ cnt2,
                         float* __restrict__ easum, int E)
{
    int idx = blockIdx.x * blockDim.x + threadIdx.x;
    if (idx < 262144) {
        int j = idx & 7, lane = (idx >> 3) & 63, fn = (idx >> 9) & 3, wid = (idx >> 11) & 3, t = idx >> 13;
        int c = wid * 64 + fn * 16 + (lane & 15);
        int k = t * 32 + (lane >> 4) * 8 + j;
        float v = (c < 128) ? sWl[(size_t)k * 128 + c] : sWr[(size_t)k * 128 + (c - 128)];
        Btp[idx] = f2bf(v);
        return;
    }
    idx -= 262144;
    if (idx < 36864) {
        int j = idx & 7, lane = (idx >> 3) & 63, fn = (idx >> 9) & 3, q = idx >> 11;
        int wid = q % 3, t = q / 3;
        int c = wid * 64 + fn * 16 + (lane & 15);
        int k = t * 32 + (lane >> 4) * 8 + j;
        float v = (c < 168 && k < 168) ? fc1W[(size_t)k * 168 + c] : 0.0f;
        Bt1p[idx] = f2bf(v);
        return;
    }
    idx -= 36864;
    if (idx < 2560) {
        int j = idx & 7, lane = (idx >> 3) & 63, fn = idx >> 9;
        int c = fn * 16 + (lane & 15);
        int k = (lane >> 4) * 8 + j;
        float v = 0.0f;
        if (k < 20) v = (c < 40) ? g1Wl[(size_t)k * 40 + c] : g1Wr[(size_t)k * 40 + (c - 40)];
        Bg1[idx] = f2bf(v);
        return;
    }
    idx -= 2560;
    if (idx < 3072) {
        int j = idx & 7, lane = (idx >> 3) & 63, q = idx >> 9;
        int fn = q % 3, t = q / 3;
        int c = fn * 16 + (lane & 15);
        int k = t * 32 + (lane >> 4) * 8 + j;
        float v = 0.0f;
        if (k < 40 && c < 40) v = (c < 20) ? g2Wl[(size_t)k * 20 + c] : g2Wr[(size_t)k * 20 + (c - 20)];
        Bg2[idx] = f2bf(v);
        return;
    }
    idx -= 3072;
    if (idx < E) {
        atomicAdd(&cnt1[e1d[idx]], 1);
        int d2 = e2d[idx];
        atomicAdd(&cnt2[d2], 1);
        atomicAdd(&easum[d2], ef[idx]);
    }
}

// ---------- exclusive scans ----------
__global__ void scan1(const int* __restrict__ cnt1, const int* __restrict__ cnt2,
                      int* __restrict__ off1, int* __restrict__ off2,
                      int* __restrict__ bsum1, int* __restrict__ bsum2, int M)
{
    __shared__ int sh[SCAN_B];
    int y = blockIdx.y;
    const int* cnt = y ? cnt2 : cnt1;
    int* excl = y ? off2 : off1;
    int* bsum = y ? bsum2 : bsum1;
    int i = blockIdx.x * SCAN_B + threadIdx.x;
    int v = (i < M) ? cnt[i] + y : 0;
    sh[threadIdx.x] = v;
    __syncthreads();
    for (int o = 1; o < SCAN_B; o <<= 1) {
        int t = (threadIdx.x >= o) ? sh[threadIdx.x - o] : 0;
        __syncthreads();
        sh[threadIdx.x] += t;
        __syncthreads();
    }
    if (i < M) excl[i] = sh[threadIdx.x] - v;
    if (threadIdx.x == SCAN_B - 1) bsum[blockIdx.x] = sh[threadIdx.x];
}

__global__ void scan2(int* __restrict__ bsum1, int* __restrict__ bsum2, int nb)
{
    __shared__ int sh[SCAN_B];
    int* bsum = blockIdx.y ? bsum2 : bsum1;
    int v = ((int)threadIdx.x < nb) ? bsum[threadIdx.x] : 0;
    sh[threadIdx.x] = v;
    __syncthreads();
    for (int o = 1; o < SCAN_B; o <<= 1) {
        int t = (threadIdx.x >= o) ? sh[threadIdx.x - o] : 0;
        __syncthreads();
        sh[threadIdx.x] += t;
        __syncthreads();
    }
    if ((int)threadIdx.x < nb) bsum[threadIdx.x] = sh[threadIdx.x] - v;
}

__global__ void scan3(int* __restrict__ off1, int* __restrict__ off2,
                      const int* __restrict__ bsum1, const int* __restrict__ bsum2,
                      const int* __restrict__ cnt1, const int* __restrict__ cnt2,
                      const float* __restrict__ easum, float* __restrict__ ealoop, int M)
{
    int y = blockIdx.y;
    int* off = y ? off2 : off1;
    const int* bsum = y ? bsum2 : bsum1;
    const int* cnt = y ? cnt2 : cnt1;
    int i = blockIdx.x * SCAN_B + threadIdx.x;
    if (i < M) {
        int v = off[i] + bsum[blockIdx.x];
        off[i] = v;
        if (i == M - 1) off[M] = v + cnt[i] + y;
        if (y) ealoop[i] = easum[i] / fmaxf((float)cnt2[i], 1.0f);
    }
}

// ---------- stageA: gemm (B reg-dbuf) || CSR fill || GAT1 lin ----------
__global__ __launch_bounds__(256) void stageA(
    const float* __restrict__ A, const unsigned short* __restrict__ Btp,
    unsigned short* __restrict__ P,
    const int* __restrict__ e1s, const int* __restrict__ e1d,
    const int* __restrict__ e2s, const int* __restrict__ e2d,
    const float* __restrict__ ef, const float* __restrict__ ealoop,
    const int* __restrict__ off1, const int* __restrict__ off2,
    int* __restrict__ cnt1, int* __restrict__ cnt2,
    int* __restrict__ srcs1, int2* __restrict__ se2,
    const float* __restrict__ addf, const unsigned short* __restrict__ Bg1,
    const float* __restrict__ g1bl, const float* __restrict__ g1br,
    unsigned short* __restrict__ xl1b, unsigned short* __restrict__ xr1b,
    int M, int E, int Eext, int Gg, int Gf)
{
    __shared__ __align__(16) char smem[20480];
    const int bid = blockIdx.x;
    const int tid = threadIdx.x;

    if (bid < Gg) {
        // ===== GEMM: A via reg-staged LDS dbuf; B double-buffered in REGISTERS.
        // bcur is retired by the previous barrier's compiler wait => compute never
        // stalls on B; the A prefetch (newest vmem) survives every wait.
        typedef unsigned short As2_t[64][72];
        As2_t* As2 = reinterpret_cast<As2_t*>(smem);
        const int wid = tid >> 6, lane = tid & 63;
        const int m0 = bid * 64;
        const int l16 = lane & 15, g = lane >> 4;
        const int colbase = wid * 64 + l16;
        const short8* Bv = reinterpret_cast<const short8*>(Btp);
        const int srow = tid >> 4, scol = (tid & 15) * 4;

        f32x4 acc[4][4] = {};
        float4 rcur[4], rnext[4];
        short8 bcur[2][4], bnext[2][4];

        // prolog: A0 -> LDS0, bcur = B(0), rcur = A1
#pragma unroll
        for (int p = 0; p < 4; ++p) {
            int ar = m0 + p * 16 + srow;
            rcur[p] = make_float4(0.f, 0.f, 0.f, 0.f);
            if (ar < M) rcur[p] = *reinterpret_cast<const float4*>(&A[(size_t)ar * 1024 + scol]);
        }
#pragma unroll
        for (int t = 0; t < 2; ++t)
#pragma unroll
            for (int fn = 0; fn < 4; ++fn)
                bcur[t][fn] = Bv[((t * 4 + wid) * 4 + fn) * 64 + lane];
#pragma unroll
        for (int p = 0; p < 4; ++p) {
            ushort4 u;
            u.x = f2bf(rcur[p].x); u.y = f2bf(rcur[p].y); u.z = f2bf(rcur[p].z); u.w = f2bf(rcur[p].w);
            *reinterpret_cast<ushort4*>(&As2[0][p * 16 + srow][scol]) = u;
        }
#pragma unroll
        for (int p = 0; p < 4; ++p) {
            int ar = m0 + p * 16 + srow;
            rcur[p] = make_float4(0.f, 0.f, 0.f, 0.f);
            if (ar < M) rcur[p] = *reinterpret_cast<const float4*>(&A[(size_t)ar * 1024 + 64 + scol]);
        }
        BAR_LGKM();

        for (int c = 0; c < 16; ++c) {
            const int buf = c & 1;
            // 1) B for chunk c+1 -> registers (oldest vmem of this chunk)
            if (c < 15) {
#pragma unroll
                for (int t = 0; t < 2; ++t)
#pragma unroll
                    for (int fn = 0; fn < 4; ++fn)
                        bnext[t][fn] = Bv[((((c + 1) * 2 + t) * 4 + wid) * 4 + fn) * 64 + lane];
            }
            // 2) A prefetch for chunk c+2 (newest vmem -> survives all waits)
            if (c < 14) {
                const int k0 = (c + 2) * 64;
#pragma unroll
                for (int p = 0; p < 4; ++p) {
                    int ar = m0 + p * 16 + srow;
                    rnext[p] = make_float4(0.f, 0.f, 0.f, 0.f);
                    if (ar < M) rnext[p] = *reinterpret_cast<const float4*>(&A[(size_t)ar * 1024 + k0 + scol]);
                }
            }
            // 3) compute: B from registers (no wait), A from LDS
#pragma unroll
            for (int t = 0; t < 2; ++t) {
                short8 afr[4];
#pragma unroll
                for (int fm = 0; fm < 4; ++fm)
                    afr[fm] = *reinterpret_cast<const short8*>(&As2[buf][fm * 16 + l16][t * 32 + g * 8]);
#pragma unroll
                for (int fm = 0; fm < 4; ++fm)
#pragma unroll
                    for (int fn = 0; fn < 4; ++fn)
                        acc[fm][fn] = __builtin_amdgcn_mfma_f32_16x16x32_bf16(
                            afr[fm], bcur[t][fn], acc[fm][fn], 0, 0, 0);
            }
            // 4) stage A chunk c+1 (rcur loads are the oldest vmem -> cheap wait)
            if (c < 15) {
#pragma unroll
                for (int p = 0; p < 4; ++p) {
                    ushort4 u;
                    u.x = f2bf(rcur[p].x); u.y = f2bf(rcur[p].y);
                    u.z = f2bf(rcur[p].z); u.w = f2bf(rcur[p].w);
                    *reinterpret_cast<ushort4*>(&As2[buf ^ 1][p * 16 + srow][scol]) = u;
                }
            }
            // 5) LDS-only barrier
            BAR_LGKM();
#pragma unroll
            for (int p = 0; p < 4; ++p) rcur[p] = rnext[p];
#pragma unroll
            for (int t = 0; t < 2; ++t)
#pragma unroll
                for (int fn = 0; fn < 4; ++fn) bcur[t][fn] = bnext[t][fn];
        }

#pragma unroll
        for (int fm = 0; fm < 4; ++fm) {
#pragma unroll
            for (int r = 0; r < 4; ++r) {
                int row = m0 + fm * 16 + g * 4 + r;
                if (row < M) {
#pragma unroll
                    for (int fn = 0; fn < 4; ++fn)
                        P[(size_t)row * 256 + colbase + fn * 16] = f2bf(acc[fm][fn][r]);
                }
            }
        }
    } else if (bid < Gg + Gf) {
        // ===== CSR fill path =====
        int t = (bid - Gg) * 256 + tid;
        if (t < E) {
            int d = e1d[t];
            int pos = atomicSub(&cnt1[d], 1) - 1;
            srcs1[off1[d] + pos] = e1s[t];
        }
        int t2 = t - E;
        if (t2 >= 0 && t2 < Eext) {
            if (t2 < E) {
                int d = e2d[t2];
                int pos = atomicSub(&cnt2[d], 1) - 1;
                se2[off2[d] + pos] = make_int2(e2s[t2], __float_as_int(ef[t2]));
            } else {
                int nn = t2 - E;
                se2[off2[nn + 1] - 1] = make_int2(nn, __float_as_int(ealoop[nn]));
            }
        }
    } else {
        // ===== GAT1 linear path: 4 waves, each one 64-row tile; bf16 out, PAD=16 =====
        const int wid = tid >> 6, lane = tid & 63;
        const int tile = (bid - Gg - Gf) * 4 + wid;
        const int m0 = tile * 64;
        if (m0 >= M) return;
        unsigned short (*xs)[40] = reinterpret_cast<unsigned short(*)[40]>(smem + wid * 5120);
        const int l16 = lane & 15, g = lane >> 4;
        const short8* Bv = reinterpret_cast<const short8*>(Bg1);

#pragma unroll
        for (int i = 0; i < 5; ++i) {
            int q = i * 64 + lane;
            int f = q * 4;
            int row = f / 20, col = f % 20;
            int ar = m0 + row;
            float4 v = make_float4(0.f, 0.f, 0.f, 0.f);
            if (ar < M) v = *reinterpret_cast<const float4*>(&addf[(size_t)ar * 20 + col]);
            ushort4 u;
            u.x = f2bf(v.x); u.y = f2bf(v.y); u.z = f2bf(v.z); u.w = f2bf(v.w);
            *reinterpret_cast<ushort4*>(&xs[row][col]) = u;
        }
        ushort4 zz; zz.x = 0; zz.y = 0; zz.z = 0; zz.w = 0;
#pragma unroll
        for (int c = 20; c < 32; c += 4)
            *reinterpret_cast<ushort4*>(&xs[lane][c]) = zz;

        f32x4 acc[4][5] = {};
        short8 afr[4], bfr[5];
#pragma unroll
        for (int fm = 0; fm < 4; ++fm)
            afr[fm] = *reinterpret_cast<const short8*>(&xs[fm * 16 + l16][g * 8]);
#pragma unroll
        for (int fn = 0; fn < 5; ++fn)
            bfr[fn] = Bv[fn * 64 + lane];
#pragma unroll
        for (int fm = 0; fm < 4; ++fm)
#pragma unroll
            for (int fn = 0; fn < 5; ++fn)
                acc[fm][fn] = __builtin_amdgcn_mfma_f32_16x16x32_bf16(
                    afr[fm], bfr[fn], acc[fm][fn], 0, 0, 0);

#pragma unroll
        for (int fm = 0; fm < 4; ++fm) {
#pragma unroll
            for (int r = 0; r < 4; ++r) {
                int row = m0 + fm * 16 + g * 4 + r;
                if (row < M) {
#pragma unroll
                    for (int fn = 0; fn < 5; ++fn) {
                        int col = fn * 16 + l16;
                        float v = acc[fm][fn][r];
                        if (col < 40) {
                            int h = col / 10, c = col % 10;
                            xl1b[((size_t)row * 4 + h) * 16 + c] = f2bf(v + g1bl[col]);
                        } else if (col < 80) {
                            int cc = col - 40, h = cc / 10, c = cc % 10;
                            xr1b[((size_t)row * 4 + h) * 16 + c] = f2bf(v + g1br[cc]);
                        }
                    }
                }
            }
        }
    }
}

// ---------- fused GATv2 node core (device helper) ----------
template <int H, int C, int BPAD>
__device__ __forceinline__ void gat_node_compute(
    const int2* __restrict__ se2, const int* __restrict__ off2,
    const unsigned short* __restrict__ xlb, const unsigned short* __restrict__ xrb,
    const float* __restrict__ We, const float* __restrict__ att,
    int n, int h, float* __restrict__ outc)
{
    float xrc[C], atth[C], weh[C];
    {
        short8 sv[BPAD / 8];
#pragma unroll
        for (int q = 0; q < BPAD / 8; ++q)
            sv[q] = *reinterpret_cast<const short8*>(&xrb[((size_t)n * H + h) * BPAD + q * 8]);
#pragma unroll
        for (int c = 0; c < C; ++c) xrc[c] = bf2f((unsigned short)sv[c / 8][c % 8]);
    }
#pragma unroll
    for (int c = 0; c < C; ++c) {
        atth[c] = att[h * C + c];
        weh[c]  = We[h * C + c];
    }

    const int beg = off2[n], end = off2[n + 1];
    float mx = -FLT_MAX, den = 0.0f;
    float accv[C] = {};
    for (int j = beg; j < end; ++j) {
        int2 se = se2[j];
        int s = se.x;
        float ea = __int_as_float(se.y);
        short8 sv[BPAD / 8];
#pragma unroll
        for (int q = 0; q < BPAD / 8; ++q)
            sv[q] = *reinterpret_cast<const short8*>(&xlb[((size_t)s * H + h) * BPAD + q * 8]);
        float xv[C];
        float lg = 0.0f;
#pragma unroll
        for (int c = 0; c < C; ++c) {
            xv[c] = bf2f((unsigned short)sv[c / 8][c % 8]);
            float m = xv[c] + xrc[c] + ea * weh[c];
            lg += lrelu(m, 0.2f) * atth[c];
        }
        if (lg > mx) {
            float sc = __expf(mx - lg);
            den *= sc;
#pragma unroll
            for (int c = 0; c < C; ++c) accv[c] *= sc;
            mx = lg;
        }
        float ex = __expf(lg - mx);
        den += ex;
#pragma unroll
        for (int c = 0; c < C; ++c) accv[c] += ex * xv[c];
    }
    float inv = 1.0f / (den + 1e-16f);
#pragma unroll
    for (int c = 0; c < C; ++c) outc[c] = accv[c] * inv;
}

// ---------- stageB: sage_gather (blocks [0,Gg)) || gat_node1 + GAT2-lin fused (rest) ----------
__global__ __launch_bounds__(256) void stageB(
    const int* __restrict__ srcs1, const int* __restrict__ off1,
    const unsigned short* __restrict__ P, const float* __restrict__ bl,
    const float* __restrict__ bng, const float* __restrict__ bnb,
    unsigned short* __restrict__ z128,
    const int2* __restrict__ se2, const int* __restrict__ off2,
    const unsigned short* __restrict__ xl1b, const unsigned short* __restrict__ xr1b,
    const float* __restrict__ g1We, const float* __restrict__ g1att,
    const float* __restrict__ g1b,
    const unsigned short* __restrict__ Bg2,
    const float* __restrict__ g2bl, const float* __restrict__ g2br,
    unsigned short* __restrict__ xl2b, unsigned short* __restrict__ xr2b,
    int N, int Gg)
{
    __shared__ unsigned short xs[64][72];
    const int bid = blockIdx.x;
    const int tid = threadIdx.x;
    if (bid < Gg) {
        int t = bid * 256 + tid;
        if (t >= N * 16) return;
        int n = t >> 4, g = t & 15;
        int beg = off1[n], end = off1[n + 1];
        float a[8] = {};
        for (int j = beg; j < end; ++j) {
            int s = srcs1[j];
            short8 v = *reinterpret_cast<const short8*>(&P[(size_t)s * 256 + g * 8]);
#pragma unroll
            for (int k = 0; k < 8; ++k) a[k] += bf2f((unsigned short)v[k]);
        }
        float inv = 1.0f / fmaxf((float)(end - beg), 1.0f);
        short8 pr = *reinterpret_cast<const short8*>(&P[(size_t)n * 256 + 128 + g * 8]);
        short8 zo;
#pragma unroll
        for (int k = 0; k < 8; ++k) {
            int cc = g * 8 + k;
            float x = a[k] * inv + bl[cc] + bf2f((unsigned short)pr[k]);
            x = x * (bng[cc] * BN_RSQ) + bnb[cc];
            zo[k] = (short)f2bf(lrelu(x, 0.01f));
        }
        *reinterpret_cast<short8*>(&z128[(size_t)n * 128 + g * 8]) = zo;
    } else {
        // node1 for 64 nodes, then GAT2 linear on those rows from LDS (y1 never hits HBM)
        const int m0 = (bid - Gg) * 64;
        ushort4 zz; zz.x = 0; zz.y = 0; zz.z = 0; zz.w = 0;
#pragma unroll
        for (int i = 0; i < 5; ++i) {
            int idx = i * 256 + tid;
            if (idx < 1152) reinterpret_cast<ushort4*>(&xs[0][0])[idx] = zz;
        }
        __syncthreads();
        {
            int row = tid >> 2, h = tid & 3;
            int n = m0 + row;
            if (n < N) {
                float oc[10];
                gat_node_compute<4, 10, 16>(se2, off2, xl1b, xr1b, g1We, g1att, n, h, oc);
#pragma unroll
                for (int c = 0; c < 10; ++c) {
                    int jch = h * 10 + c;
                    xs[row][jch] = f2bf(lrelu(oc[c] + g1b[jch], 0.01f));
                }
            }
        }
        __syncthreads();
        // GAT2 linear: waves 0..2 each own fragment-col fn=wid (K=40 pad 64 -> 2 ksteps)
        const int wid = tid >> 6, lane = tid & 63;
        const int l16 = lane & 15, g = lane >> 4;
        if (wid < 3) {
            const short8* Bv = reinterpret_cast<const short8*>(Bg2);
            f32x4 acc[4] = {};
#pragma unroll
            for (int t = 0; t < 2; ++t) {
                short8 bfr = Bv[(t * 3 + wid) * 64 + lane];
#pragma unroll
                for (int fm = 0; fm < 4; ++fm) {
                    short8 afr = *reinterpret_cast<const short8*>(&xs[fm * 16 + l16][t * 32 + g * 8]);
                    acc[fm] = __builtin_amdgcn_mfma_f32_16x16x32_bf16(afr, bfr, acc[fm], 0, 0, 0);
                }
            }
#pragma unroll
            for (int fm = 0; fm < 4; ++fm) {
#pragma unroll
                for (int r = 0; r < 4; ++r) {
                    int row = m0 + fm * 16 + g * 4 + r;
                    if (row < N) {
                        int col = wid * 16 + l16;
                        float v = acc[fm][r];
                        if (col < 20) {
                            int h = col / 5, c = col % 5;
                            xl2b[((size_t)row * 4 + h) * 8 + c] = f2bf(v + g2bl[col]);
                        } else if (col < 40) {
                            int cc = col - 20, h = cc / 5, c = cc % 5;
                            xr2b[((size_t)row * 4 + h) * 8 + c] = f2bf(v + g2br[cc]);
                        }
                    }
                }
            }
        }
    }
}

// ---------- MLP head via MFMA, with GAT2-node fused (1 node-head per thread) ----------
__global__ __launch_bounds__(256) void mlp_mfma(
    const unsigned short* __restrict__ z128, const float* __restrict__ addf,
    const int2* __restrict__ se2, const int* __restrict__ off2,
    const unsigned short* __restrict__ xl2b, const unsigned short* __restrict__ xr2b,
    const float* __restrict__ g2We, const float* __restrict__ g2att,
    const float* __restrict__ g2b,
    const float* __restrict__ bnyg, const float* __restrict__ bnyb,
    const unsigned short* __restrict__ Bt1p,
    const float* __restrict__ fc1b, const float* __restrict__ bnfg, const float* __restrict__ bnfb,
    const float* __restrict__ fc2W, const float* __restrict__ fc2b,
    float* __restrict__ out, int M)
{
    __shared__ __align__(16) char smem[64 * 169 * 4];
    unsigned short (*zs)[200] = reinterpret_cast<unsigned short(*)[200]>(smem);
    float (*ts)[169] = reinterpret_cast<float(*)[169]>(smem);
    const int tid = threadIdx.x;
    const int wid = tid >> 6, lane = tid & 63;
    const int m0 = blockIdx.x * 64;
    const int l16 = lane & 15, g = lane >> 4;
    const short8* Bv = reinterpret_cast<const short8*>(Bt1p);

    {
        int row = tid >> 2, h = tid & 3;
        int n = m0 + row;
        if (n < M) {
            float oc[5];
            gat_node_compute<4, 5, 8>(se2, off2, xl2b, xr2b, g2We, g2att, n, h, oc);
#pragma unroll
            for (int c = 0; c < 5; ++c) {
                int jch = h * 5 + c;
                float v = oc[c] + g2b[jch];
                v = v * (bnyg[jch] * BN_RSQ) + bnyb[jch];
                zs[row][128 + jch] = f2bf(lrelu(v, 0.01f));
            }
        } else {
#pragma unroll
            for (int c = 0; c < 5; ++c) zs[row][128 + h * 5 + c] = 0;
        }
    }

#pragma unroll
    for (int p = 0; p < 13; ++p) {
        int idx = p * 256 + tid;
        if (idx < 3200) {
            int row = idx / 50, c4 = (idx % 50) * 4;
            if (c4 >= 128 && c4 < 148) continue;
            int ar = m0 + row;
            ushort4 u; u.x = 0; u.y = 0; u.z = 0; u.w = 0;
            if (ar < M) {
                if (c4 < 128) {
                    u = *reinterpret_cast<const ushort4*>(&z128[(size_t)ar * 128 + c4]);
                } else if (c4 >= 148 && c4 < 168) {
                    float4 v = *reinterpret_cast<const float4*>(&addf[(size_t)ar * 20 + (c4 - 148)]);
                    u.x = f2bf(v.x); u.y = f2bf(v.y); u.z = f2bf(v.z); u.w = f2bf(v.w);
                }
            }
            *reinterpret_cast<ushort4*>(&zs[row][c4]) = u;
        }
    }
    __syncthreads();

    f32x4 acc[4][4] = {};
    if (wid < 3) {
#pragma unroll
        for (int t = 0; t < 6; ++t) {
            short8 afr[4], bfr[4];
#pragma unroll
            for (int fm = 0; fm < 4; ++fm)
                afr[fm] = *reinterpret_cast<const short8*>(&zs[fm * 16 + l16][t * 32 + g * 8]);
#pragma unroll
            for (int fn = 0; fn < 4; ++fn)
                bfr[fn] = Bv[((t * 3 + wid) * 4 + fn) * 64 + lane];
#pragma unroll
            for (int fm = 0; fm < 4; ++fm)
#pragma unroll
                for (int fn = 0; fn < 4; ++fn)
                    acc[fm][fn] = __builtin_amdgcn_mfma_f32_16x16x32_bf16(
                        afr[fm], bfr[fn], acc[fm][fn], 0, 0, 0);
        }
    }
    __syncthreads();
    if (wid < 3) {
        const int colbase = wid * 64 + l16;
#pragma unroll
        for (int fm = 0; fm < 4; ++fm) {
#pragma unroll
            for (int r = 0; r < 4; ++r) {
                int rr = fm * 16 + g * 4 + r;
#pragma unroll
                for (int fn = 0; fn < 4; ++fn) {
                    int col = colbase + fn * 16;
                    if (col < 168) {
                        float v = acc[fm][fn][r] + fc1b[col];
                        v = v * (bnfg[col] * BN_RSQ) + bnfb[col];
                        ts[rr][col] = fmaxf(v, 0.0f);
                    }
                }
            }
        }
    }
    __syncthreads();
    if (tid < 192) {
        int r = tid & 63, c = tid >> 6;
        float acc2 = fc2b[c];
#pragma unroll 4
        for (int k = 0; k < 168; ++k) acc2 += ts[r][k] * fc2W[k * 3 + c];
        int row = m0 + r;
        if (row < M) out[(size_t)row * 3 + c] = acc2;
    }
}

// ---------- launch ----------
extern "C" void kernel_launch(void* const* d_in, const int* in_sizes, int n_in,
                              void* d_out, int out_size, void* d_ws, size_t ws_size,
                              hipStream_t stream)
{
    const float* features = (const float*)d_in[0];
    const int*   e1       = (const int*)d_in[1];
    const int*   e2       = (const int*)d_in[2];
    const float* ef       = (const float*)d_in[3];
    const float* addf     = (const float*)d_in[4];
    const float* sage_Wl  = (const float*)d_in[5];
    const float* sage_bl  = (const float*)d_in[6];
    const float* sage_Wr  = (const float*)d_in[7];
    const float* g1_Wl = (const float*)d_in[8];
    const float* g1_bl = (const float*)d_in[9];
    const float* g1_Wr = (const float*)d_in[10];
    const float* g1_br = (const float*)d_in[11];
    const float* g1_We = (const float*)d_in[12];
    const float* g1_att = (const float*)d_in[13];
    const float* g1_b = (const float*)d_in[14];
    const float* g2_Wl = (const float*)d_in[15];
    const float* g2_bl = (const float*)d_in[16];
    const float* g2_Wr = (const float*)d_in[17];
    const float* g2_br = (const float*)d_in[18];
    const float* g2_We = (const float*)d_in[19];
    const float* g2_att = (const float*)d_in[20];
    const float* g2_b = (const float*)d_in[21];
    const float* fc1_W = (const float*)d_in[22];
    const float* fc1_b = (const float*)d_in[23];
    const float* fc2_W = (const float*)d_in[24];
    const float* fc2_b = (const float*)d_in[25];
    const float* bnx_g = (const float*)d_in[26];
    const float* bnx_b = (const float*)d_in[27];
    const float* bny_g = (const float*)d_in[28];
    const float* bny_b = (const float*)d_in[29];
    const float* bnf_g = (const float*)d_in[30];
    const float* bnf_b = (const float*)d_in[31];

    const int N = in_sizes[0] / 1024;
    const int E = in_sizes[3];
    const int Eext = E + N;
    const int* e1s = e1, *e1d = e1 + E;
    const int* e2s = e2, *e2d = e2 + E;
    const int nb = (N + SCAN_B - 1) / SCAN_B;

    char* wb = (char*)d_ws;
    size_t off = 0;
    auto takeB = [&](size_t bytes) { char* p = wb + off; off = (off + bytes + 255) & ~(size_t)255; return p; };
    unsigned short* P = (unsigned short*)takeB((size_t)N * 256 * 2);
    unsigned short* z128 = (unsigned short*)takeB((size_t)N * 128 * 2);
    float* ealoop = (float*)takeB((size_t)N * 4);
    unsigned short* xl1b = (unsigned short*)takeB((size_t)N * 64 * 2);
    unsigned short* xr1b = (unsigned short*)takeB((size_t)N * 64 * 2);
    unsigned short* xl2b = (unsigned short*)takeB((size_t)N * 32 * 2);
    unsigned short* xr2b = (unsigned short*)takeB((size_t)N * 32 * 2);
    unsigned short* Btp  = (unsigned short*)takeB((size_t)256 * 1024 * 2);
    unsigned short* Bt1p = (unsigned short*)takeB((size_t)36864 * 2);
    unsigned short* Bg1  = (unsigned short*)takeB((size_t)2560 * 2);
    unsigned short* Bg2  = (unsigned short*)takeB((size_t)3072 * 2);
    char* zero_beg = wb + off;
    int* cnt1    = (int*)takeB((size_t)N * 4);
    int* cnt2    = (int*)takeB((size_t)N * 4);
    float* easum = (float*)takeB((size_t)N * 4);
    size_t zero_len = (size_t)((wb + off) - zero_beg);
    int* off1  = (int*)takeB((size_t)(N + 1) * 4);
    int* off2  = (int*)takeB((size_t)(N + 1) * 4);
    int* bsum1 = (int*)takeB(SCAN_B * 4);
    int* bsum2 = (int*)takeB(SCAN_B * 4);
    int* srcs1 = (int*)takeB((size_t)E * 4);
    int2* se2  = (int2*)takeB((size_t)Eext * 8);

    const int B = 256;
    const int n16 = (int)(zero_len / 16);
    zero_ws<<<(n16 + B - 1) / B, B, 0, stream>>>((uint4*)zero_beg, n16);

    const int prep_total = 262144 + 36864 + 2560 + 3072 + E;
    prep_all<<<(prep_total + B - 1) / B, B, 0, stream>>>(
        sage_Wl, sage_Wr, Btp, fc1_W, Bt1p,
        g1_Wl, g1_Wr, Bg1, g2_Wl, g2_Wr, Bg2,
        e1d, e2d, ef, cnt1, cnt2, easum, E);

    scan1<<<dim3(nb, 2), SCAN_B, 0, stream>>>(cnt1, cnt2, off1, off2, bsum1, bsum2, N);
    scan2<<<dim3(1, 2), SCAN_B, 0, stream>>>(bsum1, bsum2, nb);
    scan3<<<dim3(nb, 2), SCAN_B, 0, stream>>>(off1, off2, bsum1, bsum2, cnt1, cnt2,
                                              easum, ealoop, N);

    // stageA: gemm || CSR fill || gat_lin1
    const int mtiles = (N + 63) / 64;
    const int Gf = (E + Eext + B - 1) / B;
    const int Gl = (mtiles + 3) / 4;
    stageA<<<mtiles + Gf + Gl, 256, 0, stream>>>(
        features, Btp, P,
        e1s, e1d, e2s, e2d, ef, ealoop, off1, off2, cnt1, cnt2, srcs1, se2,
        addf, Bg1, g1_bl, g1_br, xl1b, xr1b,
        N, E, Eext, mtiles, Gf);

    // stageB: sage_gather || (gat_node1 + GAT2 linear fused)
    const int Gg = (N * 16 + B - 1) / B;
    const int Gn = (N * 4 + B - 1) / B;
    stageB<<<Gg + Gn, 256, 0, stream>>>(
        srcs1, off1, P, sage_bl, bnx_g, bnx_b, z128,
        se2, off2, xl1b, xr1b, g1_We, g1_att, g1_b,
        Bg2, g2_bl, g2_br, xl2b, xr2b, N, Gg);

    // mlp with GAT2-node fused
    mlp_mfma<<<mtiles, 256, 0, stream>>>(
        z128, addf, se2, off2, xl2b, xr2b, g2_We, g2_att, g2_b, bny_g, bny_b,
        Bt1p, fc1_b, bnf_g, bnf_b, fc2_W, fc2_b, (float*)d_out, N);
}